// Round 7
// baseline (443.654 us; speedup 1.0000x reference)
//
#include <hip/hip_runtime.h>
#include <math.h>
#include <stdint.h>

// EncoderLayer on MI355X — Round 6:
// - GEMM: 2-phase-per-K-tile interleave (m201-style): per phase {ds_read
//   frags + stage-issue -> s_barrier -> setprio MFMA cluster -> s_barrier},
//   counted vmcnt(2) once per tile. 4 raw barriers/tile, no full drains.
// - attn: V LDS hash-swizzle (row^(row>>3))&7 kills ~8-way write conflicts;
//   lrun computed by MFMA against a ones-row block appended to V^T (removes
//   the 31-op sum tree); setprio around QK^T and PV clusters.

#define D_MODEL 1024
#define N_HEADS 16
#define DKH     64
#define D_FF    4096
#define BATCH   4
#define SEQ     2048
#define NTOK    (BATCH * SEQ)   // 8192
#define LN_EPS  1e-5f
#define QKV_LD  3072
#define QSCALE  0.18033688011112042f   // 0.125 * log2(e)

typedef unsigned short u16;
typedef __attribute__((ext_vector_type(8))) short bf16x8;
typedef __attribute__((ext_vector_type(4))) float f32x4;
typedef __attribute__((ext_vector_type(16))) float f32x16;

__device__ __forceinline__ u16 f2bf(float f) {
    union { float f; uint32_t u; } c; c.f = f;
    return (u16)((c.u + 0x7FFFu + ((c.u >> 16) & 1u)) >> 16);   // RNE
}
__device__ __forceinline__ float bf2f(u16 h) {
    union { uint32_t u; float f; } c; c.u = ((uint32_t)h) << 16;
    return c.f;
}

// async global->LDS, 16B/lane; lds base wave-uniform, HW writes base+lane*16
__device__ __forceinline__ void gload16(const u16* g, u16* lds) {
    __builtin_amdgcn_global_load_lds(
        (const __attribute__((address_space(1))) uint32_t*)g,
        (__attribute__((address_space(3))) uint32_t*)(uintptr_t)lds,
        16, 0, 0);
}

__device__ __forceinline__ void store_out(float* p, float v) { *p = v; }
__device__ __forceinline__ void store_out(u16* p, float v)   { *p = f2bf(v); }

// ---------------------------------------------------------------------------
// Pipelined bf16 GEMM: C[M,N] = A[M,K] @ Bt[N,K]^T + bias.
// MODE: 0 none, 1 relu, 2 qkv (region bias + Q-scale).
// BM=128, BN=256, BK=64, 512 thr = 8 waves (2M x 4N), 64x64 out per wave.
// LDS: A 3 bufs, B 2 bufs, chunk^row&7 swizzle. 2 phases per K-tile, each
// {ds_read + stage-issue | barrier | 16 MFMA | barrier}; vmcnt(2) tile end.
// ---------------------------------------------------------------------------
template <int MODE, typename OutT>
__global__ __launch_bounds__(512) void gemm_pipe_kernel(
    const u16* __restrict__ A, const u16* __restrict__ Bt,
    const float* __restrict__ bias, const float* __restrict__ bias2,
    const float* __restrict__ bias3, OutT* __restrict__ C,
    int M, int N, int K)
{
    __shared__ u16 lds[3 * 8192 + 2 * 16384];   // 112 KB

    const int tid  = threadIdx.x;
    const int wave = tid >> 6;
    const int lane = tid & 63;
    const int lo   = lane & 15;
    const int hi   = lane >> 4;
    const int wr   = wave >> 2;         // 0..1
    const int wc   = wave & 3;          // 0..3

    // XCD-aware swizzle (nwg always %8==0 here)
    const int gx  = gridDim.x;
    const int nwg = gx * gridDim.y;
    int bid = blockIdx.y * gx + blockIdx.x;
    bid = (bid & 7) * (nwg >> 3) + (bid >> 3);
    const int m0 = (bid / gx) << 7;
    const int n0 = (bid % gx) << 8;
    const int NT = K >> 6;

    const int srow = lane >> 3;
    const int schk = (lane & 7) ^ srow;
    const u16* AgS = A  + (size_t)(m0 + wave * 16 + srow) * K + schk * 8;
    const u16* BgS = Bt + (size_t)(n0 + wave * 32 + srow) * K + schk * 8;
    u16* AdS = lds + wave * 1024;
    u16* BdS = lds + 24576 + wave * 2048;

    auto stageA = [&](int kt, int buf) {
        const u16* g = AgS + kt * 64;
        u16* d = AdS + buf * 8192;
#pragma unroll
        for (int q = 0; q < 2; ++q)
            gload16(g + (size_t)q * 8 * K, d + q * 512);
    };
    auto stageB = [&](int kt, int buf) {
        const u16* g = BgS + kt * 64;
        u16* d = BdS + buf * 16384;
#pragma unroll
        for (int q = 0; q < 4; ++q)
            gload16(g + (size_t)q * 8 * K, d + q * 512);
    };

    f32x4 acc[4][4];
#pragma unroll
    for (int i = 0; i < 4; ++i)
#pragma unroll
        for (int j = 0; j < 4; ++j)
#pragma unroll
            for (int r = 0; r < 4; ++r) acc[i][j][r] = 0.f;

    // prologue: A(0), B(0), A(1) in flight; wait leaves A(1)'s 2 loads live
    stageA(0, 0);
    stageB(0, 0);
    stageA(1, 1);
    __builtin_amdgcn_sched_barrier(0);
    asm volatile("s_waitcnt vmcnt(2)" ::: "memory");
    __builtin_amdgcn_s_barrier();
    __builtin_amdgcn_sched_barrier(0);

    for (int t = 0; t < NT; ++t) {
        int tb = t + 1; if (tb >= NT) tb = 0;
        int ta = t + 2; if (ta >= NT) ta -= NT;
        const u16* Ab = lds + (t % 3) * 8192;
        const u16* Bb = lds + 24576 + (t & 1) * 16384;

        // ---- phase 0 (ks=0) ----
        bf16x8 a0[4], b0[4];
#pragma unroll
        for (int i = 0; i < 4; ++i) {
            const int ar = wr * 64 + i * 16 + lo;
            a0[i] = *(const bf16x8*)&Ab[ar * 64 + ((hi ^ (ar & 7)) << 3)];
            const int br = wc * 64 + i * 16 + lo;
            b0[i] = *(const bf16x8*)&Bb[br * 64 + ((hi ^ (br & 7)) << 3)];
        }
        stageB(tb, (t + 1) & 1);
        __builtin_amdgcn_sched_barrier(0);
        __builtin_amdgcn_s_barrier();
        __builtin_amdgcn_sched_barrier(0);
        __builtin_amdgcn_s_setprio(1);
#pragma unroll
        for (int i = 0; i < 4; ++i)
#pragma unroll
            for (int j = 0; j < 4; ++j)
                acc[i][j] = __builtin_amdgcn_mfma_f32_16x16x32_bf16(
                                a0[i], b0[j], acc[i][j], 0, 0, 0);
        __builtin_amdgcn_s_setprio(0);
        __builtin_amdgcn_sched_barrier(0);
        __builtin_amdgcn_s_barrier();
        __builtin_amdgcn_sched_barrier(0);

        // ---- phase 1 (ks=1) ----
        bf16x8 a1[4], b1[4];
#pragma unroll
        for (int i = 0; i < 4; ++i) {
            const int ar = wr * 64 + i * 16 + lo;
            a1[i] = *(const bf16x8*)&Ab[ar * 64 + (((4 + hi) ^ (ar & 7)) << 3)];
            const int br = wc * 64 + i * 16 + lo;
            b1[i] = *(const bf16x8*)&Bb[br * 64 + (((4 + hi) ^ (br & 7)) << 3)];
        }
        stageA(ta, (t + 2) % 3);
        __builtin_amdgcn_sched_barrier(0);
        __builtin_amdgcn_s_barrier();
        __builtin_amdgcn_sched_barrier(0);
        __builtin_amdgcn_s_setprio(1);
#pragma unroll
        for (int i = 0; i < 4; ++i)
#pragma unroll
            for (int j = 0; j < 4; ++j)
                acc[i][j] = __builtin_amdgcn_mfma_f32_16x16x32_bf16(
                                a1[i], b1[j], acc[i][j], 0, 0, 0);
        __builtin_amdgcn_s_setprio(0);
        __builtin_amdgcn_sched_barrier(0);
        asm volatile("s_waitcnt vmcnt(2)" ::: "memory");
        __builtin_amdgcn_s_barrier();
        __builtin_amdgcn_sched_barrier(0);
    }

    // epilogue: C/D layout col=lane&15, row=(lane>>4)*4+reg
    const int crow0 = m0 + wr * 64 + hi * 4;
    const int ccol0 = n0 + wc * 64 + lo;
#pragma unroll
    for (int j = 0; j < 4; ++j) {
        const int col = ccol0 + j * 16;
        float bj;
        float sc = 1.0f;
        if (MODE == 2) {
            bj = (col < 1024) ? bias[col]
               : (col < 2048) ? bias2[col - 1024] : bias3[col - 2048];
            if (col < 1024) sc = QSCALE;
        } else {
            bj = bias[col];
        }
#pragma unroll
        for (int i = 0; i < 4; ++i)
#pragma unroll
            for (int r = 0; r < 4; ++r) {
                float v = acc[i][j][r] + bj;
                if (MODE == 1) v = fmaxf(v, 0.f);
                if (MODE == 2) v *= sc;
                store_out(&C[(size_t)(crow0 + i * 16 + r) * N + col], v);
            }
    }
}

// ---------------------------------------------------------------------------
// Flash attention, swapped QK^T on 32x32x16 MFMA. Double-buffered K/V.
// V^T LDS has 32 extra rows: row 64 = 1.0 (ones), 65..95 = 0 — a third PV
// accumulator oacc2 then yields the softmax denominator via MFMA (row 64).
// V write/read chunk swizzle: hash(row) = (row ^ (row>>3)) & 7 (conflict-free
// write pattern; same hash on read).
// ---------------------------------------------------------------------------
__global__ __launch_bounds__(256, 4) void attn_mfma_kernel(
    const u16* __restrict__ QKV, u16* __restrict__ O)
{
    __shared__ u16 Klds[2][64 * 64];   // [kv][dk]
    __shared__ u16 Vlds[2][96 * 64];   // [dk][kv]; rows 64..95 = ones block

    const int tid  = threadIdx.x;
    const int wave = tid >> 6;
    const int lane = tid & 63;
    const int l31  = lane & 31;
    const int hi5  = lane >> 5;
    const int b    = blockIdx.x >> 4;
    const int h    = blockIdx.x & 15;
    const int q0   = blockIdx.y * 128 + wave * 32;
    const size_t rowb = (size_t)b * SEQ * QKV_LD + (size_t)h * DKH;
    const u16* Qg = QKV + rowb;
    const u16* Kg = QKV + rowb + 1024;
    const u16* Vg = QKV + rowb + 2048;

    // ones/zeros block init (rows 64..95 of both V buffers), once
    {
        const int ibuf = tid >> 7;
        const int irow = 64 + ((tid >> 2) & 31);
        const uint32_t ival = (irow == 64) ? 0x3F803F80u : 0u;
        const uint4 iv = make_uint4(ival, ival, ival, ival);
        *(uint4*)&Vlds[ibuf][irow * 64 + (tid & 3) * 16]     = iv;
        *(uint4*)&Vlds[ibuf][irow * 64 + (tid & 3) * 16 + 8] = iv;
    }

    // Q as B-operand: col(q) = l31, k = 16f + 8*hi5 + e
    bf16x8 qf[4];
#pragma unroll
    for (int f = 0; f < 4; ++f)
        qf[f] = *(const bf16x8*)&Qg[(size_t)(q0 + l31) * QKV_LD + 16 * f + 8 * hi5];

    f32x16 oacc[2];
    f32x16 oacc2;
#pragma unroll
    for (int g = 0; g < 2; ++g)
#pragma unroll
        for (int r = 0; r < 16; ++r) oacc[g][r] = 0.f;
#pragma unroll
    for (int r = 0; r < 16; ++r) oacc2[r] = 0.f;
    float mrun = -1e30f;

    // K staging via gload16 with pre-swizzled source (chunk ^ row&7)
    const int krow = wave * 8 + (lane >> 3);
    const int kchk = ((lane & 7) ^ (lane >> 3)) << 3;

    // V transpose staging: thread owns 4 kv x 4 dk
    const int vdk0 = (tid & 15) * 4;
    const int vkv  = (tid >> 4) * 4;
    const int vchk = vkv >> 3;
    const int vsub = vkv & 7;

    // read-side hashes (rows l31 / 32+l31; hash(64+l31) == hash(l31))
    const int ha = (l31 ^ (l31 >> 3)) & 7;
    const int hb = ha ^ 4;

    alignas(8) u16 e[4][4];   // in-flight V block (issue-early, write-late)

    auto stageK = [&](int kv0, int buf) {
        u16* kdst = &Klds[buf][wave * 512];
        gload16(Kg + (size_t)(kv0 + krow) * QKV_LD + kchk,      kdst);
        gload16(Kg + (size_t)(kv0 + krow + 32) * QKV_LD + kchk, kdst + 32 * 64);
    };
    auto loadV = [&](int kv0) {
#pragma unroll
        for (int i = 0; i < 4; ++i)
            *(uint2*)e[i] = *(const uint2*)&Vg[(size_t)(kv0 + vkv + i) * QKV_LD + vdk0];
    };
    auto writeV = [&](int buf) {
#pragma unroll
        for (int j = 0; j < 4; ++j) {
            alignas(8) u16 w4[4] = { e[0][j], e[1][j], e[2][j], e[3][j] };
            const int row = vdk0 + j;
            const int hsh = (row ^ (row >> 3)) & 7;
            *(uint2*)&Vlds[buf][row * 64 + ((vchk ^ hsh) << 3) + vsub] =
                *(const uint2*)w4;
        }
    };

    // prologue: tile 0 into buf 0
    stageK(0, 0);
    loadV(0);
    writeV(0);
    __syncthreads();

    constexpr int NTILES = SEQ / 64;
    for (int t = 0; t < NTILES; ++t) {
        const int cur = t & 1, nxt = cur ^ 1;
        if (t + 1 < NTILES) {              // issue next tile's loads NOW
            stageK((t + 1) * 64, nxt);
            loadV((t + 1) * 64);
        }

        // S^T = K·Q (exp2 units, scale folded into Q)
        f32x16 s0, s1;
#pragma unroll
        for (int r = 0; r < 16; ++r) { s0[r] = 0.f; s1[r] = 0.f; }
        __builtin_amdgcn_s_setprio(1);
#pragma unroll
        for (int f = 0; f < 4; ++f) {
            const int rc = ((2 * f + hi5) ^ (l31 & 7)) << 3;
            const bf16x8 ka = *(const bf16x8*)&Klds[cur][l31 * 64 + rc];
            const bf16x8 kb = *(const bf16x8*)&Klds[cur][(32 + l31) * 64 + rc];
            s0 = __builtin_amdgcn_mfma_f32_32x32x16_bf16(ka, qf[f], s0, 0, 0, 0);
            s1 = __builtin_amdgcn_mfma_f32_32x32x16_bf16(kb, qf[f], s1, 0, 0, 0);
        }
        __builtin_amdgcn_s_setprio(0);

        // tree max, one cross-lane exchange for the pair
        float mx[16];
#pragma unroll
        for (int r = 0; r < 16; ++r) mx[r] = fmaxf(s0[r], s1[r]);
#pragma unroll
        for (int off = 8; off >= 1; off >>= 1)
#pragma unroll
            for (int r = 0; r < off; ++r) mx[r] = fmaxf(mx[r], mx[r + off]);
        float tm = fmaxf(mx[0], __shfl_xor(mx[0], 32, 64));
        if (__any(tm > mrun + 8.0f)) {              // defer-max (T13)
            const float mnew = fmaxf(mrun, tm);
            const float corr = exp2f(mrun - mnew);
#pragma unroll
            for (int g = 0; g < 2; ++g)
#pragma unroll
                for (int r = 0; r < 16; ++r) oacc[g][r] *= corr;
            oacc2[0] *= corr;                       // denominator rides reg 0
            mrun = mnew;
        }
#pragma unroll
        for (int r = 0; r < 16; ++r) {
            s0[r] = exp2f(s0[r] - mrun);
            s1[r] = exp2f(s1[r] - mrun);
        }

        if (t + 1 < NTILES) writeV(nxt);   // vmcnt wait lands here, post-softmax

        // P B-frags via cvt_pk + permlane32_swap
        auto mkfrag = [&](float a0, float a1, float a2, float a3,
                          float a4, float a5, float a6, float a7) -> bf16x8 {
            uint32_t A, B, C, D;
            asm("v_cvt_pk_bf16_f32 %0, %1, %2" : "=v"(A) : "v"(a0), "v"(a1));
            asm("v_cvt_pk_bf16_f32 %0, %1, %2" : "=v"(C) : "v"(a2), "v"(a3));
            asm("v_cvt_pk_bf16_f32 %0, %1, %2" : "=v"(B) : "v"(a4), "v"(a5));
            asm("v_cvt_pk_bf16_f32 %0, %1, %2" : "=v"(D) : "v"(a6), "v"(a7));
            asm volatile("v_permlane32_swap_b32 %0, %1" : "+v"(A), "+v"(B));
            asm volatile("v_permlane32_swap_b32 %0, %1" : "+v"(C), "+v"(D));
            union { uint32_t w[4]; bf16x8 v; } u;
            u.w[0] = A; u.w[1] = C; u.w[2] = B; u.w[3] = D;
            return u.v;
        };
        bf16x8 pb0 = mkfrag(s0[0], s0[1], s0[2],  s0[3],  s0[4],  s0[5],  s0[6],  s0[7]);
        bf16x8 pb1 = mkfrag(s0[8], s0[9], s0[10], s0[11], s0[12], s0[13], s0[14], s0[15]);
        bf16x8 pb2 = mkfrag(s1[0], s1[1], s1[2],  s1[3],  s1[4],  s1[5],  s1[6],  s1[7]);
        bf16x8 pb3 = mkfrag(s1[8], s1[9], s1[10], s1[11], s1[12], s1[13], s1[14], s1[15]);

        // O^T += V^T · P  (+ ones-row block for the denominator)
        __builtin_amdgcn_s_setprio(1);
#pragma unroll
        for (int f = 0; f < 4; ++f) {
            const bf16x8 pf = (f == 0) ? pb0 : (f == 1) ? pb1 : (f == 2) ? pb2 : pb3;
            const int ca = ((2 * f + hi5) ^ ha) << 3;
            const int cb = ((2 * f + hi5) ^ hb) << 3;
            const bf16x8 va = *(const bf16x8*)&Vlds[cur][l31 * 64 + ca];
            const bf16x8 vb = *(const bf16x8*)&Vlds[cur][(32 + l31) * 64 + cb];
            const bf16x8 vc = *(const bf16x8*)&Vlds[cur][(64 + l31) * 64 + ca];
            oacc[0] = __builtin_amdgcn_mfma_f32_32x32x16_bf16(va, pf, oacc[0], 0, 0, 0);
            oacc[1] = __builtin_amdgcn_mfma_f32_32x32x16_bf16(vb, pf, oacc[1], 0, 0, 0);
            oacc2   = __builtin_amdgcn_mfma_f32_32x32x16_bf16(vc, pf, oacc2,   0, 0, 0);
        }
        __builtin_amdgcn_s_setprio(0);
        __syncthreads();   // nxt buffers ready; cur reads done before overwrite
    }

    // denominator: row 64 -> oacc2[0] on hi5=0 lanes (other half holds 0)
    float lr = oacc2[0];
    lr += __shfl_xor(lr, 32, 64);
    const float inv = 1.0f / lr;
    u16* Orow = O + (size_t)b * SEQ * D_MODEL + (size_t)(q0 + l31) * D_MODEL + h * DKH;
#pragma unroll
    for (int g = 0; g < 2; ++g)
#pragma unroll
        for (int rp = 0; rp < 8; ++rp) {
            const int r = rp * 2;
            const float v0 = oacc[g][r] * inv;
            const float v1 = oacc[g][r + 1] * inv;
            uint32_t pk;
            asm("v_cvt_pk_bf16_f32 %0, %1, %2" : "=v"(pk) : "v"(v0), "v"(v1));
            const int d = 32 * g + (r & 3) + 8 * (r >> 2) + 4 * hi5;
            *(uint32_t*)&Orow[d] = pk;
        }
}

// ---------------------------------------------------------------------------
// W[K][N] f32 -> Wt[N][K] bf16 (tiled 32x32 transpose)
// ---------------------------------------------------------------------------
__global__ __launch_bounds__(256) void transpose_w_kernel(
    const float* __restrict__ W, u16* __restrict__ Wt, int K, int N)
{
    __shared__ float t[32][33];
    const int n0 = blockIdx.x << 5;
    const int k0 = blockIdx.y << 5;
    const int tx = threadIdx.x & 31;
    const int ty = threadIdx.x >> 5;
#pragma unroll
    for (int i = 0; i < 4; ++i)
        t[ty + i * 8][tx] = W[(size_t)(k0 + ty + i * 8) * N + n0 + tx];
    __syncthreads();
#pragma unroll
    for (int i = 0; i < 4; ++i)
        Wt[(size_t)(n0 + ty + i * 8) * K + k0 + tx] = f2bf(t[tx][ty + i * 8]);
}

// f32 -> bf16 bulk convert, 8 elems/thread
__global__ __launch_bounds__(256) void cvt_kernel(
    const float* __restrict__ src, u16* __restrict__ dst)
{
    const size_t i = ((size_t)blockIdx.x * 256 + threadIdx.x) * 8;
    const float4 a = *(const float4*)&src[i];
    const float4 b = *(const float4*)&src[i + 4];
    alignas(16) u16 e[8] = { f2bf(a.x), f2bf(a.y), f2bf(a.z), f2bf(a.w),
                             f2bf(b.x), f2bf(b.y), f2bf(b.z), f2bf(b.w) };
    *(int4*)&dst[i] = *(const int4*)e;
}

// ---------------------------------------------------------------------------
// out = LayerNorm(X + Y)*gamma + beta; mixed dtypes. One block per row.
// ---------------------------------------------------------------------------
__device__ __forceinline__ float4 ld4(const float* p) { return *(const float4*)p; }
__device__ __forceinline__ float4 ld4(const u16* p) {
    alignas(8) u16 e[4];
    *(uint2*)e = *(const uint2*)p;
    return make_float4(bf2f(e[0]), bf2f(e[1]), bf2f(e[2]), bf2f(e[3]));
}
__device__ __forceinline__ void st4(float* p, float4 v) { *(float4*)p = v; }
__device__ __forceinline__ void st4(u16* p, float4 v) {
    alignas(8) u16 e[4] = { f2bf(v.x), f2bf(v.y), f2bf(v.z), f2bf(v.w) };
    *(uint2*)p = *(const uint2*)e;
}

template <typename XT, typename YT, typename OT>
__global__ __launch_bounds__(256) void add_ln_kernel(
    const XT* __restrict__ X, const YT* __restrict__ Y,
    const float* __restrict__ gamma, const float* __restrict__ beta,
    OT* __restrict__ Out)
{
    const int row = blockIdx.x;
    const int i0  = threadIdx.x << 2;
    const float4 xv = ld4(X + (size_t)row * D_MODEL + i0);
    const float4 yv = ld4(Y + (size_t)row * D_MODEL + i0);
    const float4 v  = make_float4(xv.x + yv.x, xv.y + yv.y, xv.z + yv.z, xv.w + yv.w);

    float s1 = v.x + v.y + v.z + v.w;
    float s2 = v.x * v.x + v.y * v.y + v.z * v.z + v.w * v.w;
#pragma unroll
    for (int off = 32; off > 0; off >>= 1) {
        s1 += __shfl_xor(s1, off, 64);
        s2 += __shfl_xor(s2, off, 64);
    }
    __shared__ float red[8];
    const int wid = threadIdx.x >> 6;
    if ((threadIdx.x & 63) == 0) { red[wid] = s1; red[wid + 4] = s2; }
    __syncthreads();
    s1 = red[0] + red[1] + red[2] + red[3];
    s2 = red[4] + red[5] + red[6] + red[7];

    const float mu   = s1 * (1.0f / D_MODEL);
    const float var  = s2 * (1.0f / D_MODEL) - mu * mu;
    const float rstd = rsqrtf(var + LN_EPS);

    const float4 g  = *(const float4*)(gamma + i0);
    const float4 bb = *(const float4*)(beta + i0);
    float4 ov;
    ov.x = (v.x - mu) * rstd * g.x + bb.x;
    ov.y = (v.y - mu) * rstd * g.y + bb.y;
    ov.z = (v.z - mu) * rstd * g.z + bb.z;
    ov.w = (v.w - mu) * rstd * g.w + bb.w;
    st4(Out + (size_t)row * D_MODEL + i0, ov);
}

// ---------------------------------------------------------------------------
extern "C" void kernel_launch(void* const* d_in, const int* in_sizes, int n_in,
                              void* d_out, int out_size, void* d_ws, size_t ws_size,
                              hipStream_t stream)
{
    const float* x     = (const float*)d_in[0];
    const float* Wq    = (const float*)d_in[1];
    const float* bq    = (const float*)d_in[2];
    const float* Wk    = (const float*)d_in[3];
    const float* bk    = (const float*)d_in[4];
    const float* Wv    = (const float*)d_in[5];
    const float* bv    = (const float*)d_in[6];
    const float* Wo    = (const float*)d_in[7];
    const float* bo    = (const float*)d_in[8];
    const float* W1    = (const float*)d_in[9];
    const float* b1    = (const float*)d_in[10];
    const float* W2    = (const float*)d_in[11];
    const float* b2    = (const float*)d_in[12];
    const float* g1    = (const float*)d_in[13];
    const float* beta1 = (const float*)d_in[14];
    const float* g2    = (const float*)d_in[15];
    const float* beta2 = (const float*)d_in[16];
    float* out = (float*)d_out;

    const size_t TOKD = (size_t)NTOK * D_MODEL;
    u16* xb    = (u16*)d_ws;
    u16* wqkvT = xb + TOKD;                              // [3072][1024]
    u16* woT   = wqkvT + (size_t)3 * D_MODEL * D_MODEL;
    u16* w1T   = woT + (size_t)D_MODEL * D_MODEL;        // [4096][1024]
    u16* w2T   = w1T + (size_t)D_MODEL * D_FF;           // [1024][4096]
    u16* qkv   = w2T + (size_t)D_FF * D_MODEL;           // [NTOK][3072]
    u16* ctx   = qkv + (size_t)NTOK * QKV_LD;
    u16* y1    = ctx + TOKD;
    u16* x2    = y1;                                     // LN1 in place
    u16* h1    = qkv;                                    // spans qkv+ctx

    const dim3 blk(256);
    const dim3 blk5(512);

    cvt_kernel<<<dim3(TOKD / 2048), blk, 0, stream>>>(x, xb);
    transpose_w_kernel<<<dim3(D_MODEL / 32, D_MODEL / 32), blk, 0, stream>>>(Wq, wqkvT, D_MODEL, D_MODEL);
    transpose_w_kernel<<<dim3(D_MODEL / 32, D_MODEL / 32), blk, 0, stream>>>(Wk, wqkvT + (size_t)D_MODEL * D_MODEL, D_MODEL, D_MODEL);
    transpose_w_kernel<<<dim3(D_MODEL / 32, D_MODEL / 32), blk, 0, stream>>>(Wv, wqkvT + (size_t)2 * D_MODEL * D_MODEL, D_MODEL, D_MODEL);
    transpose_w_kernel<<<dim3(D_MODEL / 32, D_MODEL / 32), blk, 0, stream>>>(Wo, woT, D_MODEL, D_MODEL);
    transpose_w_kernel<<<dim3(D_FF / 32,    D_MODEL / 32), blk, 0, stream>>>(W1, w1T, D_MODEL, D_FF);
    transpose_w_kernel<<<dim3(D_MODEL / 32, D_FF / 32),    blk, 0, stream>>>(W2, w2T, D_FF, D_MODEL);

    // fused QKV projection (Q pre-scaled for exp2 softmax)
    gemm_pipe_kernel<2, u16><<<dim3(QKV_LD / 256, NTOK / 128), blk5, 0, stream>>>(
        xb, wqkvT, bq, bk, bv, qkv, NTOK, QKV_LD, D_MODEL);

    attn_mfma_kernel<<<dim3(BATCH * N_HEADS, SEQ / 128), blk, 0, stream>>>(qkv, ctx);

    gemm_pipe_kernel<0, u16><<<dim3(D_MODEL / 256, NTOK / 128), blk5, 0, stream>>>(
        ctx, woT, bo, bo, bo, y1, NTOK, D_MODEL, D_MODEL);

    add_ln_kernel<float, u16, u16><<<dim3(NTOK), blk, 0, stream>>>(x, y1, g1, beta1, x2);

    gemm_pipe_kernel<1, u16><<<dim3(D_FF / 256, NTOK / 128), blk5, 0, stream>>>(
        x2, w1T, b1, b1, b1, h1, NTOK, D_FF, D_MODEL);
    gemm_pipe_kernel<0, float><<<dim3(D_MODEL / 256, NTOK / 128), blk5, 0, stream>>>(
        h1, w2T, b2, b2, b2, out, NTOK, D_MODEL, D_FF);

    add_ln_kernel<u16, float, float><<<dim3(NTOK), blk, 0, stream>>>(x2, out, g2, beta2, out);

    (void)in_sizes; (void)n_in; (void)out_size; (void)ws_size;
}

// Round 8
// 393.812 us; speedup vs baseline: 1.1266x; 1.1266x over previous
//
#include <hip/hip_runtime.h>
#include <math.h>
#include <stdint.h>

// EncoderLayer on MI355X — Round 7: revert-to-best + proven deltas only.
// - GEMM: round-5 pipeline (BM128xBN256xBK64, counted vmcnt(2), XCD swizzle,
//   setprio, single compute region per K-tile).
// - attn: round-4 single-buffer structure (best measured) + V hash-swizzle
//   (row^(row>>3))&7 (proven: conflicts 2.3e7 -> 6.4e6) + tree reductions +
//   setprio. No ones-block, no double-buffer (both measured regressions).

#define D_MODEL 1024
#define N_HEADS 16
#define DKH     64
#define D_FF    4096
#define BATCH   4
#define SEQ     2048
#define NTOK    (BATCH * SEQ)   // 8192
#define LN_EPS  1e-5f
#define QKV_LD  3072
#define QSCALE  0.18033688011112042f   // 0.125 * log2(e)

typedef unsigned short u16;
typedef __attribute__((ext_vector_type(8))) short bf16x8;
typedef __attribute__((ext_vector_type(4))) float f32x4;
typedef __attribute__((ext_vector_type(16))) float f32x16;

__device__ __forceinline__ u16 f2bf(float f) {
    union { float f; uint32_t u; } c; c.f = f;
    return (u16)((c.u + 0x7FFFu + ((c.u >> 16) & 1u)) >> 16);   // RNE
}
__device__ __forceinline__ float bf2f(u16 h) {
    union { uint32_t u; float f; } c; c.u = ((uint32_t)h) << 16;
    return c.f;
}

// async global->LDS, 16B/lane; lds base wave-uniform, HW writes base+lane*16
__device__ __forceinline__ void gload16(const u16* g, u16* lds) {
    __builtin_amdgcn_global_load_lds(
        (const __attribute__((address_space(1))) uint32_t*)g,
        (__attribute__((address_space(3))) uint32_t*)(uintptr_t)lds,
        16, 0, 0);
}

__device__ __forceinline__ void store_out(float* p, float v) { *p = v; }
__device__ __forceinline__ void store_out(u16* p, float v)   { *p = f2bf(v); }

// ---------------------------------------------------------------------------
// Pipelined bf16 GEMM: C[M,N] = A[M,K] @ Bt[N,K]^T + bias.
// MODE: 0 none, 1 relu, 2 qkv (region bias + Q-scale).
// BM=128, BN=256, BK=64, 512 thr = 8 waves (2M x 4N), 64x64 out per wave.
// LDS: A 3 bufs, B 2 bufs, chunk^row&7 swizzle. vmcnt(2) at boundaries only.
// Block index XCD-swizzled (grid always %8==0 here).
// ---------------------------------------------------------------------------
template <int MODE, typename OutT>
__global__ __launch_bounds__(512) void gemm_pipe_kernel(
    const u16* __restrict__ A, const u16* __restrict__ Bt,
    const float* __restrict__ bias, const float* __restrict__ bias2,
    const float* __restrict__ bias3, OutT* __restrict__ C,
    int M, int N, int K)
{
    __shared__ u16 lds[3 * 8192 + 2 * 16384];   // 112 KB

    const int tid  = threadIdx.x;
    const int wave = tid >> 6;
    const int lane = tid & 63;
    const int lo   = lane & 15;
    const int hi   = lane >> 4;
    const int wr   = wave >> 2;         // 0..1
    const int wc   = wave & 3;          // 0..3

    const int gx  = gridDim.x;
    const int nwg = gx * gridDim.y;
    int bid = blockIdx.y * gx + blockIdx.x;
    bid = (bid & 7) * (nwg >> 3) + (bid >> 3);
    const int m0 = (bid / gx) << 7;
    const int n0 = (bid % gx) << 8;
    const int NT = K >> 6;

    const int srow = lane >> 3;
    const int schk = (lane & 7) ^ srow;
    const u16* AgS = A  + (size_t)(m0 + wave * 16 + srow) * K + schk * 8;
    const u16* BgS = Bt + (size_t)(n0 + wave * 32 + srow) * K + schk * 8;
    u16* AdS = lds + wave * 1024;
    u16* BdS = lds + 24576 + wave * 2048;

    auto stageA = [&](int kt, int buf) {
        const u16* g = AgS + kt * 64;
        u16* d = AdS + buf * 8192;
#pragma unroll
        for (int q = 0; q < 2; ++q)
            gload16(g + (size_t)q * 8 * K, d + q * 512);
    };
    auto stageB = [&](int kt, int buf) {
        const u16* g = BgS + kt * 64;
        u16* d = BdS + buf * 16384;
#pragma unroll
        for (int q = 0; q < 4; ++q)
            gload16(g + (size_t)q * 8 * K, d + q * 512);
    };

    f32x4 acc[4][4];
#pragma unroll
    for (int i = 0; i < 4; ++i)
#pragma unroll
        for (int j = 0; j < 4; ++j)
#pragma unroll
            for (int r = 0; r < 4; ++r) acc[i][j][r] = 0.f;

    // prologue: A(0), B(0), A(1) -> wait leaves A(1)'s 2 loads in flight
    stageA(0, 0);
    stageB(0, 0);
    stageA(1, 1);
    __builtin_amdgcn_sched_barrier(0);
    asm volatile("s_waitcnt vmcnt(2)" ::: "memory");
    __builtin_amdgcn_s_barrier();
    __builtin_amdgcn_sched_barrier(0);

    for (int t = 0; t < NT; ++t) {
        int tb = t + 1; if (tb >= NT) tb = 0;
        int ta = t + 2; if (ta >= NT) ta -= NT;
        stageB(tb, (t + 1) & 1);
        stageA(ta, (t + 2) % 3);

        const u16* Ab = lds + (t % 3) * 8192;
        const u16* Bb = lds + 24576 + (t & 1) * 16384;
#pragma unroll
        for (int ks = 0; ks < 2; ++ks) {
            bf16x8 a[4], b[4];
#pragma unroll
            for (int i = 0; i < 4; ++i) {
                const int ar = wr * 64 + i * 16 + lo;
                a[i] = *(const bf16x8*)&Ab[ar * 64 + (((ks * 4 + hi) ^ (ar & 7)) << 3)];
                const int br = wc * 64 + i * 16 + lo;
                b[i] = *(const bf16x8*)&Bb[br * 64 + (((ks * 4 + hi) ^ (br & 7)) << 3)];
            }
            __builtin_amdgcn_s_setprio(1);
#pragma unroll
            for (int i = 0; i < 4; ++i)
#pragma unroll
                for (int j = 0; j < 4; ++j)
                    acc[i][j] = __builtin_amdgcn_mfma_f32_16x16x32_bf16(
                                    a[i], b[j], acc[i][j], 0, 0, 0);
            __builtin_amdgcn_s_setprio(0);
        }
        __builtin_amdgcn_sched_barrier(0);
        asm volatile("s_waitcnt vmcnt(2)" ::: "memory");
        __builtin_amdgcn_s_barrier();
        __builtin_amdgcn_sched_barrier(0);
    }

    // epilogue: C/D layout col=lane&15, row=(lane>>4)*4+reg
    const int crow0 = m0 + wr * 64 + hi * 4;
    const int ccol0 = n0 + wc * 64 + lo;
#pragma unroll
    for (int j = 0; j < 4; ++j) {
        const int col = ccol0 + j * 16;
        float bj;
        float sc = 1.0f;
        if (MODE == 2) {
            bj = (col < 1024) ? bias[col]
               : (col < 2048) ? bias2[col - 1024] : bias3[col - 2048];
            if (col < 1024) sc = QSCALE;
        } else {
            bj = bias[col];
        }
#pragma unroll
        for (int i = 0; i < 4; ++i)
#pragma unroll
            for (int r = 0; r < 4; ++r) {
                float v = acc[i][j][r] + bj;
                if (MODE == 1) v = fmaxf(v, 0.f);
                if (MODE == 2) v *= sc;
                store_out(&C[(size_t)(crow0 + i * 16 + r) * N + col], v);
            }
    }
}

// ---------------------------------------------------------------------------
// Flash attention, swapped QK^T on 32x32x16 MFMA. Single-buffered K/V
// (measured best), V chunk hash-swizzle (row^(row>>3))&7 on write AND read.
// ---------------------------------------------------------------------------
__global__ __launch_bounds__(256, 4) void attn_mfma_kernel(
    const u16* __restrict__ QKV, u16* __restrict__ O)
{
    __shared__ u16 Klds[64 * 64];   // [kv][dk], chunk ^ (row&7)
    __shared__ u16 Vlds[64 * 64];   // [dk][kv], chunk ^ hash(row)

    const int tid  = threadIdx.x;
    const int wave = tid >> 6;
    const int lane = tid & 63;
    const int l31  = lane & 31;
    const int hi5  = lane >> 5;
    const int b    = blockIdx.x >> 4;
    const int h    = blockIdx.x & 15;
    const int q0   = blockIdx.y * 128 + wave * 32;
    const size_t rowb = (size_t)b * SEQ * QKV_LD + (size_t)h * DKH;
    const u16* Qg = QKV + rowb;
    const u16* Kg = QKV + rowb + 1024;
    const u16* Vg = QKV + rowb + 2048;

    // Q as B-operand: col(q) = l31, k = 16f + 8*hi5 + e
    bf16x8 qf[4];
#pragma unroll
    for (int f = 0; f < 4; ++f)
        qf[f] = *(const bf16x8*)&Qg[(size_t)(q0 + l31) * QKV_LD + 16 * f + 8 * hi5];

    f32x16 oacc[2];
#pragma unroll
    for (int g = 0; g < 2; ++g)
#pragma unroll
        for (int r = 0; r < 16; ++r) oacc[g][r] = 0.f;
    float mrun = -1e30f, lrun = 0.f;

    // K staging via gload16 with pre-swizzled source (chunk ^ row&7)
    const int krow = wave * 8 + (lane >> 3);
    const int kchk = ((lane & 7) ^ (lane >> 3)) << 3;
    u16* kdst = Klds + wave * 512;

    // V transpose staging: thread owns 4 kv x 4 dk
    const int vdk0 = (tid & 15) * 4;
    const int vkv  = (tid >> 4) * 4;
    const int vchk = vkv >> 3;
    const int vsub = vkv & 7;

    // V read-side hashes: rows l31 and 32+l31
    const int ha = (l31 ^ (l31 >> 3)) & 7;
    const int hb = ha ^ 4;

    for (int kv0 = 0; kv0 < SEQ; kv0 += 64) {
        __syncthreads();
        gload16(Kg + (size_t)(kv0 + krow) * QKV_LD + kchk,      kdst);
        gload16(Kg + (size_t)(kv0 + krow + 32) * QKV_LD + kchk, kdst + 32 * 64);
        alignas(8) u16 e[4][4];
#pragma unroll
        for (int i = 0; i < 4; ++i)
            *(uint2*)e[i] = *(const uint2*)&Vg[(size_t)(kv0 + vkv + i) * QKV_LD + vdk0];
#pragma unroll
        for (int j = 0; j < 4; ++j) {
            alignas(8) u16 w4[4] = { e[0][j], e[1][j], e[2][j], e[3][j] };
            const int row = vdk0 + j;
            const int hsh = (row ^ (row >> 3)) & 7;
            *(uint2*)&Vlds[row * 64 + ((vchk ^ hsh) << 3) + vsub] = *(const uint2*)w4;
        }
        __syncthreads();

        // S^T = K·Q (exp2 units, scale folded into Q)
        f32x16 s0, s1;
#pragma unroll
        for (int r = 0; r < 16; ++r) { s0[r] = 0.f; s1[r] = 0.f; }
        __builtin_amdgcn_s_setprio(1);
#pragma unroll
        for (int f = 0; f < 4; ++f) {
            const int rc = ((2 * f + hi5) ^ (l31 & 7)) << 3;
            const bf16x8 ka = *(const bf16x8*)&Klds[l31 * 64 + rc];
            const bf16x8 kb = *(const bf16x8*)&Klds[(32 + l31) * 64 + rc];
            s0 = __builtin_amdgcn_mfma_f32_32x32x16_bf16(ka, qf[f], s0, 0, 0, 0);
            s1 = __builtin_amdgcn_mfma_f32_32x32x16_bf16(kb, qf[f], s1, 0, 0, 0);
        }
        __builtin_amdgcn_s_setprio(0);

        // tree max, one cross-lane exchange for the lane pair
        float mx[16];
#pragma unroll
        for (int r = 0; r < 16; ++r) mx[r] = fmaxf(s0[r], s1[r]);
#pragma unroll
        for (int off = 8; off >= 1; off >>= 1)
#pragma unroll
            for (int r = 0; r < off; ++r) mx[r] = fmaxf(mx[r], mx[r + off]);
        float tm = fmaxf(mx[0], __shfl_xor(mx[0], 32, 64));
        if (__any(tm > mrun + 8.0f)) {              // defer-max (T13)
            const float mnew = fmaxf(mrun, tm);
            const float corr = exp2f(mrun - mnew);
            lrun *= corr;
#pragma unroll
            for (int g = 0; g < 2; ++g)
#pragma unroll
                for (int r = 0; r < 16; ++r) oacc[g][r] *= corr;
            mrun = mnew;
        }
        float sm[16];
#pragma unroll
        for (int r = 0; r < 16; ++r) {
            s0[r] = exp2f(s0[r] - mrun);
            s1[r] = exp2f(s1[r] - mrun);
            sm[r] = s0[r] + s1[r];
        }
#pragma unroll
        for (int off = 8; off >= 1; off >>= 1)
#pragma unroll
            for (int r = 0; r < off; ++r) sm[r] += sm[r + off];
        lrun += sm[0];

        // P B-frags via cvt_pk + permlane32_swap
        auto mkfrag = [&](float a0, float a1, float a2, float a3,
                          float a4, float a5, float a6, float a7) -> bf16x8 {
            uint32_t A, B, C, D;
            asm("v_cvt_pk_bf16_f32 %0, %1, %2" : "=v"(A) : "v"(a0), "v"(a1));
            asm("v_cvt_pk_bf16_f32 %0, %1, %2" : "=v"(C) : "v"(a2), "v"(a3));
            asm("v_cvt_pk_bf16_f32 %0, %1, %2" : "=v"(B) : "v"(a4), "v"(a5));
            asm("v_cvt_pk_bf16_f32 %0, %1, %2" : "=v"(D) : "v"(a6), "v"(a7));
            asm volatile("v_permlane32_swap_b32 %0, %1" : "+v"(A), "+v"(B));
            asm volatile("v_permlane32_swap_b32 %0, %1" : "+v"(C), "+v"(D));
            union { uint32_t w[4]; bf16x8 v; } u;
            u.w[0] = A; u.w[1] = C; u.w[2] = B; u.w[3] = D;
            return u.v;
        };
        bf16x8 pb0 = mkfrag(s0[0], s0[1], s0[2],  s0[3],  s0[4],  s0[5],  s0[6],  s0[7]);
        bf16x8 pb1 = mkfrag(s0[8], s0[9], s0[10], s0[11], s0[12], s0[13], s0[14], s0[15]);
        bf16x8 pb2 = mkfrag(s1[0], s1[1], s1[2],  s1[3],  s1[4],  s1[5],  s1[6],  s1[7]);
        bf16x8 pb3 = mkfrag(s1[8], s1[9], s1[10], s1[11], s1[12], s1[13], s1[14], s1[15]);

        // O^T += V^T · P
        __builtin_amdgcn_s_setprio(1);
#pragma unroll
        for (int f = 0; f < 4; ++f) {
            const bf16x8 pf = (f == 0) ? pb0 : (f == 1) ? pb1 : (f == 2) ? pb2 : pb3;
            const int ca = ((2 * f + hi5) ^ ha) << 3;
            const int cb = ((2 * f + hi5) ^ hb) << 3;
            const bf16x8 va = *(const bf16x8*)&Vlds[l31 * 64 + ca];
            const bf16x8 vb = *(const bf16x8*)&Vlds[(32 + l31) * 64 + cb];
            oacc[0] = __builtin_amdgcn_mfma_f32_32x32x16_bf16(va, pf, oacc[0], 0, 0, 0);
            oacc[1] = __builtin_amdgcn_mfma_f32_32x32x16_bf16(vb, pf, oacc[1], 0, 0, 0);
        }
        __builtin_amdgcn_s_setprio(0);
    }

    lrun += __shfl_xor(lrun, 32, 64);
    const float inv = 1.0f / lrun;
    u16* Orow = O + (size_t)b * SEQ * D_MODEL + (size_t)(q0 + l31) * D_MODEL + h * DKH;
#pragma unroll
    for (int g = 0; g < 2; ++g)
#pragma unroll
        for (int rp = 0; rp < 8; ++rp) {
            const int r = rp * 2;
            const float v0 = oacc[g][r] * inv;
            const float v1 = oacc[g][r + 1] * inv;
            uint32_t pk;
            asm("v_cvt_pk_bf16_f32 %0, %1, %2" : "=v"(pk) : "v"(v0), "v"(v1));
            const int d = 32 * g + (r & 3) + 8 * (r >> 2) + 4 * hi5;
            *(uint32_t*)&Orow[d] = pk;
        }
}

// ---------------------------------------------------------------------------
// W[K][N] f32 -> Wt[N][K] bf16 (tiled 32x32 transpose)
// ---------------------------------------------------------------------------
__global__ __launch_bounds__(256) void transpose_w_kernel(
    const float* __restrict__ W, u16* __restrict__ Wt, int K, int N)
{
    __shared__ float t[32][33];
    const int n0 = blockIdx.x << 5;
    const int k0 = blockIdx.y << 5;
    const int tx = threadIdx.x & 31;
    const int ty = threadIdx.x >> 5;
#pragma unroll
    for (int i = 0; i < 4; ++i)
        t[ty + i * 8][tx] = W[(size_t)(k0 + ty + i * 8) * N + n0 + tx];
    __syncthreads();
#pragma unroll
    for (int i = 0; i < 4; ++i)
        Wt[(size_t)(n0 + ty + i * 8) * K + k0 + tx] = f2bf(t[tx][ty + i * 8]);
}

// f32 -> bf16 bulk convert, 8 elems/thread
__global__ __launch_bounds__(256) void cvt_kernel(
    const float* __restrict__ src, u16* __restrict__ dst)
{
    const size_t i = ((size_t)blockIdx.x * 256 + threadIdx.x) * 8;
    const float4 a = *(const float4*)&src[i];
    const float4 b = *(const float4*)&src[i + 4];
    alignas(16) u16 e[8] = { f2bf(a.x), f2bf(a.y), f2bf(a.z), f2bf(a.w),
                             f2bf(b.x), f2bf(b.y), f2bf(b.z), f2bf(b.w) };
    *(int4*)&dst[i] = *(const int4*)e;
}

// ---------------------------------------------------------------------------
// out = LayerNorm(X + Y)*gamma + beta; mixed dtypes. One block per row.
// ---------------------------------------------------------------------------
__device__ __forceinline__ float4 ld4(const float* p) { return *(const float4*)p; }
__device__ __forceinline__ float4 ld4(const u16* p) {
    alignas(8) u16 e[4];
    *(uint2*)e = *(const uint2*)p;
    return make_float4(bf2f(e[0]), bf2f(e[1]), bf2f(e[2]), bf2f(e[3]));
}
__device__ __forceinline__ void st4(float* p, float4 v) { *(float4*)p = v; }
__device__ __forceinline__ void st4(u16* p, float4 v) {
    alignas(8) u16 e[4] = { f2bf(v.x), f2bf(v.y), f2bf(v.z), f2bf(v.w) };
    *(uint2*)p = *(const uint2*)e;
}

template <typename XT, typename YT, typename OT>
__global__ __launch_bounds__(256) void add_ln_kernel(
    const XT* __restrict__ X, const YT* __restrict__ Y,
    const float* __restrict__ gamma, const float* __restrict__ beta,
    OT* __restrict__ Out)
{
    const int row = blockIdx.x;
    const int i0  = threadIdx.x << 2;
    const float4 xv = ld4(X + (size_t)row * D_MODEL + i0);
    const float4 yv = ld4(Y + (size_t)row * D_MODEL + i0);
    const float4 v  = make_float4(xv.x + yv.x, xv.y + yv.y, xv.z + yv.z, xv.w + yv.w);

    float s1 = v.x + v.y + v.z + v.w;
    float s2 = v.x * v.x + v.y * v.y + v.z * v.z + v.w * v.w;
#pragma unroll
    for (int off = 32; off > 0; off >>= 1) {
        s1 += __shfl_xor(s1, off, 64);
        s2 += __shfl_xor(s2, off, 64);
    }
    __shared__ float red[8];
    const int wid = threadIdx.x >> 6;
    if ((threadIdx.x & 63) == 0) { red[wid] = s1; red[wid + 4] = s2; }
    __syncthreads();
    s1 = red[0] + red[1] + red[2] + red[3];
    s2 = red[4] + red[5] + red[6] + red[7];

    const float mu   = s1 * (1.0f / D_MODEL);
    const float var  = s2 * (1.0f / D_MODEL) - mu * mu;
    const float rstd = rsqrtf(var + LN_EPS);

    const float4 g  = *(const float4*)(gamma + i0);
    const float4 bb = *(const float4*)(beta + i0);
    float4 ov;
    ov.x = (v.x - mu) * rstd * g.x + bb.x;
    ov.y = (v.y - mu) * rstd * g.y + bb.y;
    ov.z = (v.z - mu) * rstd * g.z + bb.z;
    ov.w = (v.w - mu) * rstd * g.w + bb.w;
    st4(Out + (size_t)row * D_MODEL + i0, ov);
}

// ---------------------------------------------------------------------------
extern "C" void kernel_launch(void* const* d_in, const int* in_sizes, int n_in,
                              void* d_out, int out_size, void* d_ws, size_t ws_size,
                              hipStream_t stream)
{
    const float* x     = (const float*)d_in[0];
    const float* Wq    = (const float*)d_in[1];
    const float* bq    = (const float*)d_in[2];
    const float* Wk    = (const float*)d_in[3];
    const float* bk    = (const float*)d_in[4];
    const float* Wv    = (const float*)d_in[5];
    const float* bv    = (const float*)d_in[6];
    const float* Wo    = (const float*)d_in[7];
    const float* bo    = (const float*)d_in[8];
    const float* W1    = (const float*)d_in[9];
    const float* b1    = (const float*)d_in[10];
    const float* W2    = (const float*)d_in[11];
    const float* b2    = (const float*)d_in[12];
    const float* g1    = (const float*)d_in[13];
    const float* beta1 = (const float*)d_in[14];
    const float* g2    = (const float*)d_in[15];
    const float* beta2 = (const float*)d_in[16];
    float* out = (float*)d_out;

    const size_t TOKD = (size_t)NTOK * D_MODEL;
    u16* xb    = (u16*)d_ws;
    u16* wqkvT = xb + TOKD;                              // [3072][1024]
    u16* woT   = wqkvT + (size_t)3 * D_MODEL * D_MODEL;
    u16* w1T   = woT + (size_t)D_MODEL * D_MODEL;        // [4096][1024]
    u16* w2T   = w1T + (size_t)D_MODEL * D_FF;           // [1024][4096]
    u16* qkv   = w2T + (size_t)D_FF * D_MODEL;           // [NTOK][3072]
    u16* ctx   = qkv + (size_t)NTOK * QKV_LD;
    u16* y1    = ctx + TOKD;
    u16* x2    = y1;                                     // LN1 in place
    u16* h1    = qkv;                                    // spans qkv+ctx

    const dim3 blk(256);
    const dim3 blk5(512);

    cvt_kernel<<<dim3(TOKD / 2048), blk, 0, stream>>>(x, xb);
    transpose_w_kernel<<<dim3(D_MODEL / 32, D_MODEL / 32), blk, 0, stream>>>(Wq, wqkvT, D_MODEL, D_MODEL);
    transpose_w_kernel<<<dim3(D_MODEL / 32, D_MODEL / 32), blk, 0, stream>>>(Wk, wqkvT + (size_t)D_MODEL * D_MODEL, D_MODEL, D_MODEL);
    transpose_w_kernel<<<dim3(D_MODEL / 32, D_MODEL / 32), blk, 0, stream>>>(Wv, wqkvT + (size_t)2 * D_MODEL * D_MODEL, D_MODEL, D_MODEL);
    transpose_w_kernel<<<dim3(D_MODEL / 32, D_MODEL / 32), blk, 0, stream>>>(Wo, woT, D_MODEL, D_MODEL);
    transpose_w_kernel<<<dim3(D_FF / 32,    D_MODEL / 32), blk, 0, stream>>>(W1, w1T, D_MODEL, D_FF);
    transpose_w_kernel<<<dim3(D_MODEL / 32, D_FF / 32),    blk, 0, stream>>>(W2, w2T, D_FF, D_MODEL);

    // fused QKV projection (Q pre-scaled for exp2 softmax)
    gemm_pipe_kernel<2, u16><<<dim3(QKV_LD / 256, NTOK / 128), blk5, 0, stream>>>(
        xb, wqkvT, bq, bk, bv, qkv, NTOK, QKV_LD, D_MODEL);

    attn_mfma_kernel<<<dim3(BATCH * N_HEADS, SEQ / 128), blk, 0, stream>>>(qkv, ctx);

    gemm_pipe_kernel<0, u16><<<dim3(D_MODEL / 256, NTOK / 128), blk5, 0, stream>>>(
        ctx, woT, bo, bo, bo, y1, NTOK, D_MODEL, D_MODEL);

    add_ln_kernel<float, u16, u16><<<dim3(NTOK), blk, 0, stream>>>(x, y1, g1, beta1, x2);

    gemm_pipe_kernel<1, u16><<<dim3(D_FF / 256, NTOK / 128), blk5, 0, stream>>>(
        x2, w1T, b1, b1, b1, h1, NTOK, D_FF, D_MODEL);
    gemm_pipe_kernel<0, float><<<dim3(D_MODEL / 256, NTOK / 128), blk5, 0, stream>>>(
        h1, w2T, b2, b2, b2, out, NTOK, D_MODEL, D_FF);

    add_ln_kernel<u16, float, float><<<dim3(NTOK), blk, 0, stream>>>(x2, out, g2, beta2, out);

    (void)in_sizes; (void)n_in; (void)out_size; (void)ws_size;
}

// Round 9
// 390.678 us; speedup vs baseline: 1.1356x; 1.0080x over previous
//
#include <hip/hip_runtime.h>
#include <math.h>
#include <stdint.h>

// EncoderLayer on MI355X — Round 8:
// - attn: single-read p-array dataflow (kills AGPR<->VGPR shuttling), MFMA
//   C-init = -mrun (saves 32 subs/tile), no launch_bounds cap (VGPR budget),
//   m_init = 0. Structure otherwise = round-7 best (single-buffer, V hash
//   swizzle, tree reductions, permlane mkfrag, setprio).
// - GEMM: round-7 pipeline unchanged (measured best).
// - misc: 4x 1024^2 weight transposes batched into one dispatch.

#define D_MODEL 1024
#define N_HEADS 16
#define DKH     64
#define D_FF    4096
#define BATCH   4
#define SEQ     2048
#define NTOK    (BATCH * SEQ)   // 8192
#define LN_EPS  1e-5f
#define QKV_LD  3072
#define QSCALE  0.18033688011112042f   // 0.125 * log2(e)

typedef unsigned short u16;
typedef __attribute__((ext_vector_type(8))) short bf16x8;
typedef __attribute__((ext_vector_type(4))) float f32x4;
typedef __attribute__((ext_vector_type(16))) float f32x16;

__device__ __forceinline__ u16 f2bf(float f) {
    union { float f; uint32_t u; } c; c.f = f;
    return (u16)((c.u + 0x7FFFu + ((c.u >> 16) & 1u)) >> 16);   // RNE
}
__device__ __forceinline__ float bf2f(u16 h) {
    union { uint32_t u; float f; } c; c.u = ((uint32_t)h) << 16;
    return c.f;
}

// async global->LDS, 16B/lane; lds base wave-uniform, HW writes base+lane*16
__device__ __forceinline__ void gload16(const u16* g, u16* lds) {
    __builtin_amdgcn_global_load_lds(
        (const __attribute__((address_space(1))) uint32_t*)g,
        (__attribute__((address_space(3))) uint32_t*)(uintptr_t)lds,
        16, 0, 0);
}

__device__ __forceinline__ void store_out(float* p, float v) { *p = v; }
__device__ __forceinline__ void store_out(u16* p, float v)   { *p = f2bf(v); }

// ---------------------------------------------------------------------------
// Pipelined bf16 GEMM (unchanged from round 7 — measured best).
// ---------------------------------------------------------------------------
template <int MODE, typename OutT>
__global__ __launch_bounds__(512) void gemm_pipe_kernel(
    const u16* __restrict__ A, const u16* __restrict__ Bt,
    const float* __restrict__ bias, const float* __restrict__ bias2,
    const float* __restrict__ bias3, OutT* __restrict__ C,
    int M, int N, int K)
{
    __shared__ u16 lds[3 * 8192 + 2 * 16384];   // 112 KB

    const int tid  = threadIdx.x;
    const int wave = tid >> 6;
    const int lane = tid & 63;
    const int lo   = lane & 15;
    const int hi   = lane >> 4;
    const int wr   = wave >> 2;
    const int wc   = wave & 3;

    const int gx  = gridDim.x;
    const int nwg = gx * gridDim.y;
    int bid = blockIdx.y * gx + blockIdx.x;
    bid = (bid & 7) * (nwg >> 3) + (bid >> 3);
    const int m0 = (bid / gx) << 7;
    const int n0 = (bid % gx) << 8;
    const int NT = K >> 6;

    const int srow = lane >> 3;
    const int schk = (lane & 7) ^ srow;
    const u16* AgS = A  + (size_t)(m0 + wave * 16 + srow) * K + schk * 8;
    const u16* BgS = Bt + (size_t)(n0 + wave * 32 + srow) * K + schk * 8;
    u16* AdS = lds + wave * 1024;
    u16* BdS = lds + 24576 + wave * 2048;

    auto stageA = [&](int kt, int buf) {
        const u16* g = AgS + kt * 64;
        u16* d = AdS + buf * 8192;
#pragma unroll
        for (int q = 0; q < 2; ++q)
            gload16(g + (size_t)q * 8 * K, d + q * 512);
    };
    auto stageB = [&](int kt, int buf) {
        const u16* g = BgS + kt * 64;
        u16* d = BdS + buf * 16384;
#pragma unroll
        for (int q = 0; q < 4; ++q)
            gload16(g + (size_t)q * 8 * K, d + q * 512);
    };

    f32x4 acc[4][4];
#pragma unroll
    for (int i = 0; i < 4; ++i)
#pragma unroll
        for (int j = 0; j < 4; ++j)
#pragma unroll
            for (int r = 0; r < 4; ++r) acc[i][j][r] = 0.f;

    stageA(0, 0);
    stageB(0, 0);
    stageA(1, 1);
    __builtin_amdgcn_sched_barrier(0);
    asm volatile("s_waitcnt vmcnt(2)" ::: "memory");
    __builtin_amdgcn_s_barrier();
    __builtin_amdgcn_sched_barrier(0);

    for (int t = 0; t < NT; ++t) {
        int tb = t + 1; if (tb >= NT) tb = 0;
        int ta = t + 2; if (ta >= NT) ta -= NT;
        stageB(tb, (t + 1) & 1);
        stageA(ta, (t + 2) % 3);

        const u16* Ab = lds + (t % 3) * 8192;
        const u16* Bb = lds + 24576 + (t & 1) * 16384;
#pragma unroll
        for (int ks = 0; ks < 2; ++ks) {
            bf16x8 a[4], b[4];
#pragma unroll
            for (int i = 0; i < 4; ++i) {
                const int ar = wr * 64 + i * 16 + lo;
                a[i] = *(const bf16x8*)&Ab[ar * 64 + (((ks * 4 + hi) ^ (ar & 7)) << 3)];
                const int br = wc * 64 + i * 16 + lo;
                b[i] = *(const bf16x8*)&Bb[br * 64 + (((ks * 4 + hi) ^ (br & 7)) << 3)];
            }
            __builtin_amdgcn_s_setprio(1);
#pragma unroll
            for (int i = 0; i < 4; ++i)
#pragma unroll
                for (int j = 0; j < 4; ++j)
                    acc[i][j] = __builtin_amdgcn_mfma_f32_16x16x32_bf16(
                                    a[i], b[j], acc[i][j], 0, 0, 0);
            __builtin_amdgcn_s_setprio(0);
        }
        __builtin_amdgcn_sched_barrier(0);
        asm volatile("s_waitcnt vmcnt(2)" ::: "memory");
        __builtin_amdgcn_s_barrier();
        __builtin_amdgcn_sched_barrier(0);
    }

    const int crow0 = m0 + wr * 64 + hi * 4;
    const int ccol0 = n0 + wc * 64 + lo;
#pragma unroll
    for (int j = 0; j < 4; ++j) {
        const int col = ccol0 + j * 16;
        float bj;
        float sc = 1.0f;
        if (MODE == 2) {
            bj = (col < 1024) ? bias[col]
               : (col < 2048) ? bias2[col - 1024] : bias3[col - 2048];
            if (col < 1024) sc = QSCALE;
        } else {
            bj = bias[col];
        }
#pragma unroll
        for (int i = 0; i < 4; ++i)
#pragma unroll
            for (int r = 0; r < 4; ++r) {
                float v = acc[i][j][r] + bj;
                if (MODE == 1) v = fmaxf(v, 0.f);
                if (MODE == 2) v *= sc;
                store_out(&C[(size_t)(crow0 + i * 16 + r) * N + col], v);
            }
    }
}

// ---------------------------------------------------------------------------
// Flash attention, swapped QK^T on 32x32x16 MFMA. Single-buffer, V hash
// swizzle. NEW: MFMA C-init = -mrun; single-read p arrays; no VGPR cap.
// ---------------------------------------------------------------------------
__global__ void attn_mfma_kernel(
    const u16* __restrict__ QKV, u16* __restrict__ O)
{
    __shared__ u16 Klds[64 * 64];   // [kv][dk], chunk ^ (row&7)
    __shared__ u16 Vlds[64 * 64];   // [dk][kv], chunk ^ hash(row)

    const int tid  = threadIdx.x;
    const int wave = tid >> 6;
    const int lane = tid & 63;
    const int l31  = lane & 31;
    const int hi5  = lane >> 5;
    const int b    = blockIdx.x >> 4;
    const int h    = blockIdx.x & 15;
    const int q0   = blockIdx.y * 128 + wave * 32;
    const size_t rowb = (size_t)b * SEQ * QKV_LD + (size_t)h * DKH;
    const u16* Qg = QKV + rowb;
    const u16* Kg = QKV + rowb + 1024;
    const u16* Vg = QKV + rowb + 2048;

    // Q as B-operand: col(q) = l31, k = 16f + 8*hi5 + e
    bf16x8 qf[4];
#pragma unroll
    for (int f = 0; f < 4; ++f)
        qf[f] = *(const bf16x8*)&Qg[(size_t)(q0 + l31) * QKV_LD + 16 * f + 8 * hi5];

    f32x16 oacc[2];
#pragma unroll
    for (int g = 0; g < 2; ++g)
#pragma unroll
        for (int r = 0; r < 16; ++r) oacc[g][r] = 0.f;
    float mrun = 0.f, lrun = 0.f;   // m_init = 0 (safe: |scores| << 100 exp2-units)

    const int krow = wave * 8 + (lane >> 3);
    const int kchk = ((lane & 7) ^ (lane >> 3)) << 3;
    u16* kdst = Klds + wave * 512;

    const int vdk0 = (tid & 15) * 4;
    const int vkv  = (tid >> 4) * 4;
    const int vchk = vkv >> 3;
    const int vsub = vkv & 7;

    const int ha = (l31 ^ (l31 >> 3)) & 7;
    const int hb = ha ^ 4;

    for (int kv0 = 0; kv0 < SEQ; kv0 += 64) {
        __syncthreads();
        gload16(Kg + (size_t)(kv0 + krow) * QKV_LD + kchk,      kdst);
        gload16(Kg + (size_t)(kv0 + krow + 32) * QKV_LD + kchk, kdst + 32 * 64);
        alignas(8) u16 e[4][4];
#pragma unroll
        for (int i = 0; i < 4; ++i)
            *(uint2*)e[i] = *(const uint2*)&Vg[(size_t)(kv0 + vkv + i) * QKV_LD + vdk0];
#pragma unroll
        for (int j = 0; j < 4; ++j) {
            alignas(8) u16 w4[4] = { e[0][j], e[1][j], e[2][j], e[3][j] };
            const int row = vdk0 + j;
            const int hsh = (row ^ (row >> 3)) & 7;
            *(uint2*)&Vlds[row * 64 + ((vchk ^ hsh) << 3) + vsub] = *(const uint2*)w4;
        }
        __syncthreads();

        // S^T - m = K·Q + C(-mrun): bias folded into the MFMA accumulator init
        f32x16 s0, s1;
        const float nm = -mrun;
#pragma unroll
        for (int r = 0; r < 16; ++r) { s0[r] = nm; s1[r] = nm; }
        __builtin_amdgcn_s_setprio(1);
#pragma unroll
        for (int f = 0; f < 4; ++f) {
            const int rc = ((2 * f + hi5) ^ (l31 & 7)) << 3;
            const bf16x8 ka = *(const bf16x8*)&Klds[l31 * 64 + rc];
            const bf16x8 kb = *(const bf16x8*)&Klds[(32 + l31) * 64 + rc];
            s0 = __builtin_amdgcn_mfma_f32_32x32x16_bf16(ka, qf[f], s0, 0, 0, 0);
            s1 = __builtin_amdgcn_mfma_f32_32x32x16_bf16(kb, qf[f], s1, 0, 0, 0);
        }
        __builtin_amdgcn_s_setprio(0);

        // single read of the accumulators into plain VGPR arrays
        float p0[16], p1[16];
#pragma unroll
        for (int r = 0; r < 16; ++r) { p0[r] = s0[r]; p1[r] = s1[r]; }

        // tree max over p (p = s - m_old)
        float mx[16];
#pragma unroll
        for (int r = 0; r < 16; ++r) mx[r] = fmaxf(p0[r], p1[r]);
#pragma unroll
        for (int off = 8; off >= 1; off >>= 1)
#pragma unroll
            for (int r = 0; r < off; ++r) mx[r] = fmaxf(mx[r], mx[r + off]);
        float tm = fmaxf(mx[0], __shfl_xor(mx[0], 32, 64));
        if (__any(tm > 8.0f)) {                 // defer-max (T13, THR=8)
            const float corr = exp2f(-tm);      // m_new = m_old + tm
            lrun *= corr;
#pragma unroll
            for (int g = 0; g < 2; ++g)
#pragma unroll
                for (int r = 0; r < 16; ++r) oacc[g][r] *= corr;
#pragma unroll
            for (int r = 0; r < 16; ++r) { p0[r] -= tm; p1[r] -= tm; }
            mrun += tm;
        }
        float sm[16];
#pragma unroll
        for (int r = 0; r < 16; ++r) {
            p0[r] = exp2f(p0[r]);
            p1[r] = exp2f(p1[r]);
            sm[r] = p0[r] + p1[r];
        }
#pragma unroll
        for (int off = 8; off >= 1; off >>= 1)
#pragma unroll
            for (int r = 0; r < off; ++r) sm[r] += sm[r + off];
        lrun += sm[0];

        // P B-frags via cvt_pk + permlane32_swap
        auto mkfrag = [&](float a0, float a1, float a2, float a3,
                          float a4, float a5, float a6, float a7) -> bf16x8 {
            uint32_t A, B, C, D;
            asm("v_cvt_pk_bf16_f32 %0, %1, %2" : "=v"(A) : "v"(a0), "v"(a1));
            asm("v_cvt_pk_bf16_f32 %0, %1, %2" : "=v"(C) : "v"(a2), "v"(a3));
            asm("v_cvt_pk_bf16_f32 %0, %1, %2" : "=v"(B) : "v"(a4), "v"(a5));
            asm("v_cvt_pk_bf16_f32 %0, %1, %2" : "=v"(D) : "v"(a6), "v"(a7));
            asm volatile("v_permlane32_swap_b32 %0, %1" : "+v"(A), "+v"(B));
            asm volatile("v_permlane32_swap_b32 %0, %1" : "+v"(C), "+v"(D));
            union { uint32_t w[4]; bf16x8 v; } u;
            u.w[0] = A; u.w[1] = C; u.w[2] = B; u.w[3] = D;
            return u.v;
        };
        bf16x8 pb0 = mkfrag(p0[0], p0[1], p0[2],  p0[3],  p0[4],  p0[5],  p0[6],  p0[7]);
        bf16x8 pb1 = mkfrag(p0[8], p0[9], p0[10], p0[11], p0[12], p0[13], p0[14], p0[15]);
        bf16x8 pb2 = mkfrag(p1[0], p1[1], p1[2],  p1[3],  p1[4],  p1[5],  p1[6],  p1[7]);
        bf16x8 pb3 = mkfrag(p1[8], p1[9], p1[10], p1[11], p1[12], p1[13], p1[14], p1[15]);

        // O^T += V^T · P
        __builtin_amdgcn_s_setprio(1);
#pragma unroll
        for (int f = 0; f < 4; ++f) {
            const bf16x8 pf = (f == 0) ? pb0 : (f == 1) ? pb1 : (f == 2) ? pb2 : pb3;
            const int ca = ((2 * f + hi5) ^ ha) << 3;
            const int cb = ((2 * f + hi5) ^ hb) << 3;
            const bf16x8 va = *(const bf16x8*)&Vlds[l31 * 64 + ca];
            const bf16x8 vb = *(const bf16x8*)&Vlds[(32 + l31) * 64 + cb];
            oacc[0] = __builtin_amdgcn_mfma_f32_32x32x16_bf16(va, pf, oacc[0], 0, 0, 0);
            oacc[1] = __builtin_amdgcn_mfma_f32_32x32x16_bf16(vb, pf, oacc[1], 0, 0, 0);
        }
        __builtin_amdgcn_s_setprio(0);
    }

    lrun += __shfl_xor(lrun, 32, 64);
    const float inv = 1.0f / lrun;
    u16* Orow = O + (size_t)b * SEQ * D_MODEL + (size_t)(q0 + l31) * D_MODEL + h * DKH;
#pragma unroll
    for (int g = 0; g < 2; ++g)
#pragma unroll
        for (int rp = 0; rp < 8; ++rp) {
            const int r = rp * 2;
            const float v0 = oacc[g][r] * inv;
            const float v1 = oacc[g][r + 1] * inv;
            uint32_t pk;
            asm("v_cvt_pk_bf16_f32 %0, %1, %2" : "=v"(pk) : "v"(v0), "v"(v1));
            const int d = 32 * g + (r & 3) + 8 * (r >> 2) + 4 * hi5;
            *(uint32_t*)&Orow[d] = pk;
        }
}

// ---------------------------------------------------------------------------
// Batched 1024x1024 transpose: z selects (Wq,Wk,Wv,Wo) -> bf16 [N][K]
// ---------------------------------------------------------------------------
__global__ __launch_bounds__(256) void transpose_w4_kernel(
    const float* __restrict__ W0, const float* __restrict__ W1,
    const float* __restrict__ W2, const float* __restrict__ W3,
    u16* __restrict__ D0, u16* __restrict__ D1,
    u16* __restrict__ D2, u16* __restrict__ D3)
{
    const int z = blockIdx.z;
    const float* W = (z == 0) ? W0 : (z == 1) ? W1 : (z == 2) ? W2 : W3;
    u16*       Wt = (z == 0) ? D0 : (z == 1) ? D1 : (z == 2) ? D2 : D3;

    __shared__ float t[32][33];
    const int n0 = blockIdx.x << 5;
    const int k0 = blockIdx.y << 5;
    const int tx = threadIdx.x & 31;
    const int ty = threadIdx.x >> 5;
#pragma unroll
    for (int i = 0; i < 4; ++i)
        t[ty + i * 8][tx] = W[(size_t)(k0 + ty + i * 8) * D_MODEL + n0 + tx];
    __syncthreads();
#pragma unroll
    for (int i = 0; i < 4; ++i)
        Wt[(size_t)(n0 + ty + i * 8) * D_MODEL + k0 + tx] = f2bf(t[tx][ty + i * 8]);
}

// W[K][N] f32 -> Wt[N][K] bf16 (generic tiled 32x32 transpose)
__global__ __launch_bounds__(256) void transpose_w_kernel(
    const float* __restrict__ W, u16* __restrict__ Wt, int K, int N)
{
    __shared__ float t[32][33];
    const int n0 = blockIdx.x << 5;
    const int k0 = blockIdx.y << 5;
    const int tx = threadIdx.x & 31;
    const int ty = threadIdx.x >> 5;
#pragma unroll
    for (int i = 0; i < 4; ++i)
        t[ty + i * 8][tx] = W[(size_t)(k0 + ty + i * 8) * N + n0 + tx];
    __syncthreads();
#pragma unroll
    for (int i = 0; i < 4; ++i)
        Wt[(size_t)(n0 + ty + i * 8) * K + k0 + tx] = f2bf(t[tx][ty + i * 8]);
}

// f32 -> bf16 bulk convert, 8 elems/thread
__global__ __launch_bounds__(256) void cvt_kernel(
    const float* __restrict__ src, u16* __restrict__ dst)
{
    const size_t i = ((size_t)blockIdx.x * 256 + threadIdx.x) * 8;
    const float4 a = *(const float4*)&src[i];
    const float4 b = *(const float4*)&src[i + 4];
    alignas(16) u16 e[8] = { f2bf(a.x), f2bf(a.y), f2bf(a.z), f2bf(a.w),
                             f2bf(b.x), f2bf(b.y), f2bf(b.z), f2bf(b.w) };
    *(int4*)&dst[i] = *(const int4*)e;
}

// ---------------------------------------------------------------------------
// out = LayerNorm(X + Y)*gamma + beta; mixed dtypes. One block per row.
// ---------------------------------------------------------------------------
__device__ __forceinline__ float4 ld4(const float* p) { return *(const float4*)p; }
__device__ __forceinline__ float4 ld4(const u16* p) {
    alignas(8) u16 e[4];
    *(uint2*)e = *(const uint2*)p;
    return make_float4(bf2f(e[0]), bf2f(e[1]), bf2f(e[2]), bf2f(e[3]));
}
__device__ __forceinline__ void st4(float* p, float4 v) { *(float4*)p = v; }
__device__ __forceinline__ void st4(u16* p, float4 v) {
    alignas(8) u16 e[4] = { f2bf(v.x), f2bf(v.y), f2bf(v.z), f2bf(v.w) };
    *(uint2*)p = *(const uint2*)e;
}

template <typename XT, typename YT, typename OT>
__global__ __launch_bounds__(256) void add_ln_kernel(
    const XT* __restrict__ X, const YT* __restrict__ Y,
    const float* __restrict__ gamma, const float* __restrict__ beta,
    OT* __restrict__ Out)
{
    const int row = blockIdx.x;
    const int i0  = threadIdx.x << 2;
    const float4 xv = ld4(X + (size_t)row * D_MODEL + i0);
    const float4 yv = ld4(Y + (size_t)row * D_MODEL + i0);
    const float4 v  = make_float4(xv.x + yv.x, xv.y + yv.y, xv.z + yv.z, xv.w + yv.w);

    float s1 = v.x + v.y + v.z + v.w;
    float s2 = v.x * v.x + v.y * v.y + v.z * v.z + v.w * v.w;
#pragma unroll
    for (int off = 32; off > 0; off >>= 1) {
        s1 += __shfl_xor(s1, off, 64);
        s2 += __shfl_xor(s2, off, 64);
    }
    __shared__ float red[8];
    const int wid = threadIdx.x >> 6;
    if ((threadIdx.x & 63) == 0) { red[wid] = s1; red[wid + 4] = s2; }
    __syncthreads();
    s1 = red[0] + red[1] + red[2] + red[3];
    s2 = red[4] + red[5] + red[6] + red[7];

    const float mu   = s1 * (1.0f / D_MODEL);
    const float var  = s2 * (1.0f / D_MODEL) - mu * mu;
    const float rstd = rsqrtf(var + LN_EPS);

    const float4 g  = *(const float4*)(gamma + i0);
    const float4 bb = *(const float4*)(beta + i0);
    float4 ov;
    ov.x = (v.x - mu) * rstd * g.x + bb.x;
    ov.y = (v.y - mu) * rstd * g.y + bb.y;
    ov.z = (v.z - mu) * rstd * g.z + bb.z;
    ov.w = (v.w - mu) * rstd * g.w + bb.w;
    st4(Out + (size_t)row * D_MODEL + i0, ov);
}

// ---------------------------------------------------------------------------
extern "C" void kernel_launch(void* const* d_in, const int* in_sizes, int n_in,
                              void* d_out, int out_size, void* d_ws, size_t ws_size,
                              hipStream_t stream)
{
    const float* x     = (const float*)d_in[0];
    const float* Wq    = (const float*)d_in[1];
    const float* bq    = (const float*)d_in[2];
    const float* Wk    = (const float*)d_in[3];
    const float* bk    = (const float*)d_in[4];
    const float* Wv    = (const float*)d_in[5];
    const float* bv    = (const float*)d_in[6];
    const float* Wo    = (const float*)d_in[7];
    const float* bo    = (const float*)d_in[8];
    const float* W1    = (const float*)d_in[9];
    const float* b1    = (const float*)d_in[10];
    const float* W2    = (const float*)d_in[11];
    const float* b2    = (const float*)d_in[12];
    const float* g1    = (const float*)d_in[13];
    const float* beta1 = (const float*)d_in[14];
    const float* g2    = (const float*)d_in[15];
    const float* beta2 = (const float*)d_in[16];
    float* out = (float*)d_out;

    const size_t TOKD = (size_t)NTOK * D_MODEL;
    u16* xb    = (u16*)d_ws;
    u16* wqkvT = xb + TOKD;                              // [3072][1024]
    u16* woT   = wqkvT + (size_t)3 * D_MODEL * D_MODEL;
    u16* w1T   = woT + (size_t)D_MODEL * D_MODEL;        // [4096][1024]
    u16* w2T   = w1T + (size_t)D_MODEL * D_FF;           // [1024][4096]
    u16* qkv   = w2T + (size_t)D_FF * D_MODEL;           // [NTOK][3072]
    u16* ctx   = qkv + (size_t)NTOK * QKV_LD;
    u16* y1    = ctx + TOKD;
    u16* x2    = y1;                                     // LN1 in place
    u16* h1    = qkv;                                    // spans qkv+ctx

    const dim3 blk(256);
    const dim3 blk5(512);

    cvt_kernel<<<dim3(TOKD / 2048), blk, 0, stream>>>(x, xb);
    transpose_w4_kernel<<<dim3(32, 32, 4), blk, 0, stream>>>(
        Wq, Wk, Wv, Wo,
        wqkvT, wqkvT + (size_t)D_MODEL * D_MODEL,
        wqkvT + (size_t)2 * D_MODEL * D_MODEL, woT);
    transpose_w_kernel<<<dim3(D_FF / 32,    D_MODEL / 32), blk, 0, stream>>>(W1, w1T, D_MODEL, D_FF);
    transpose_w_kernel<<<dim3(D_MODEL / 32, D_FF / 32),    blk, 0, stream>>>(W2, w2T, D_FF, D_MODEL);

    // fused QKV projection (Q pre-scaled for exp2 softmax)
    gemm_pipe_kernel<2, u16><<<dim3(QKV_LD / 256, NTOK / 128), blk5, 0, stream>>>(
        xb, wqkvT, bq, bk, bv, qkv, NTOK, QKV_LD, D_MODEL);

    attn_mfma_kernel<<<dim3(BATCH * N_HEADS, SEQ / 128), blk, 0, stream>>>(qkv, ctx);

    gemm_pipe_kernel<0, u16><<<dim3(D_MODEL / 256, NTOK / 128), blk5, 0, stream>>>(
        ctx, woT, bo, bo, bo, y1, NTOK, D_MODEL, D_MODEL);

    add_ln_kernel<float, u16, u16><<<dim3(NTOK), blk, 0, stream>>>(x, y1, g1, beta1, x2);

    gemm_pipe_kernel<1, u16><<<dim3(D_FF / 256, NTOK / 128), blk5, 0, stream>>>(
        x2, w1T, b1, b1, b1, h1, NTOK, D_FF, D_MODEL);
    gemm_pipe_kernel<0, float><<<dim3(D_MODEL / 256, NTOK / 128), blk5, 0, stream>>>(
        h1, w2T, b2, b2, b2, out, NTOK, D_MODEL, D_FF);

    add_ln_kernel<u16, float, float><<<dim3(NTOK), blk, 0, stream>>>(x2, out, g2, beta2, out);

    (void)in_sizes; (void)n_in; (void)out_size; (void)ws_size;
}

// Round 10
// 390.494 us; speedup vs baseline: 1.1361x; 1.0005x over previous
//
#include <hip/hip_runtime.h>
#include <math.h>
#include <stdint.h>

// EncoderLayer on MI355X — Round 8:
// - attn: single-read p-array dataflow (kills AGPR<->VGPR shuttling), MFMA
//   C-init = -mrun (saves 32 subs/tile), no launch_bounds cap (VGPR budget),
//   m_init = 0. Structure otherwise = round-7 best (single-buffer, V hash
//   swizzle, tree reductions, permlane mkfrag, setprio).
// - GEMM: round-7 pipeline unchanged (measured best).
// - misc: 4x 1024^2 weight transposes batched into one dispatch.

#define D_MODEL 1024
#define N_HEADS 16
#define DKH     64
#define D_FF    4096
#define BATCH   4
#define SEQ     2048
#define NTOK    (BATCH * SEQ)   // 8192
#define LN_EPS  1e-5f
#define QKV_LD  3072
#define QSCALE  0.18033688011112042f   // 0.125 * log2(e)

typedef unsigned short u16;
typedef __attribute__((ext_vector_type(8))) short bf16x8;
typedef __attribute__((ext_vector_type(4))) float f32x4;
typedef __attribute__((ext_vector_type(16))) float f32x16;

__device__ __forceinline__ u16 f2bf(float f) {
    union { float f; uint32_t u; } c; c.f = f;
    return (u16)((c.u + 0x7FFFu + ((c.u >> 16) & 1u)) >> 16);   // RNE
}
__device__ __forceinline__ float bf2f(u16 h) {
    union { uint32_t u; float f; } c; c.u = ((uint32_t)h) << 16;
    return c.f;
}

// async global->LDS, 16B/lane; lds base wave-uniform, HW writes base+lane*16
__device__ __forceinline__ void gload16(const u16* g, u16* lds) {
    __builtin_amdgcn_global_load_lds(
        (const __attribute__((address_space(1))) uint32_t*)g,
        (__attribute__((address_space(3))) uint32_t*)(uintptr_t)lds,
        16, 0, 0);
}

__device__ __forceinline__ void store_out(float* p, float v) { *p = v; }
__device__ __forceinline__ void store_out(u16* p, float v)   { *p = f2bf(v); }

// ---------------------------------------------------------------------------
// Pipelined bf16 GEMM (unchanged from round 7 — measured best).
// ---------------------------------------------------------------------------
template <int MODE, typename OutT>
__global__ __launch_bounds__(512) void gemm_pipe_kernel(
    const u16* __restrict__ A, const u16* __restrict__ Bt,
    const float* __restrict__ bias, const float* __restrict__ bias2,
    const float* __restrict__ bias3, OutT* __restrict__ C,
    int M, int N, int K)
{
    __shared__ u16 lds[3 * 8192 + 2 * 16384];   // 112 KB

    const int tid  = threadIdx.x;
    const int wave = tid >> 6;
    const int lane = tid & 63;
    const int lo   = lane & 15;
    const int hi   = lane >> 4;
    const int wr   = wave >> 2;
    const int wc   = wave & 3;

    const int gx  = gridDim.x;
    const int nwg = gx * gridDim.y;
    int bid = blockIdx.y * gx + blockIdx.x;
    bid = (bid & 7) * (nwg >> 3) + (bid >> 3);
    const int m0 = (bid / gx) << 7;
    const int n0 = (bid % gx) << 8;
    const int NT = K >> 6;

    const int srow = lane >> 3;
    const int schk = (lane & 7) ^ srow;
    const u16* AgS = A  + (size_t)(m0 + wave * 16 + srow) * K + schk * 8;
    const u16* BgS = Bt + (size_t)(n0 + wave * 32 + srow) * K + schk * 8;
    u16* AdS = lds + wave * 1024;
    u16* BdS = lds + 24576 + wave * 2048;

    auto stageA = [&](int kt, int buf) {
        const u16* g = AgS + kt * 64;
        u16* d = AdS + buf * 8192;
#pragma unroll
        for (int q = 0; q < 2; ++q)
            gload16(g + (size_t)q * 8 * K, d + q * 512);
    };
    auto stageB = [&](int kt, int buf) {
        const u16* g = BgS + kt * 64;
        u16* d = BdS + buf * 16384;
#pragma unroll
        for (int q = 0; q < 4; ++q)
            gload16(g + (size_t)q * 8 * K, d + q * 512);
    };

    f32x4 acc[4][4];
#pragma unroll
    for (int i = 0; i < 4; ++i)
#pragma unroll
        for (int j = 0; j < 4; ++j)
#pragma unroll
            for (int r = 0; r < 4; ++r) acc[i][j][r] = 0.f;

    stageA(0, 0);
    stageB(0, 0);
    stageA(1, 1);
    __builtin_amdgcn_sched_barrier(0);
    asm volatile("s_waitcnt vmcnt(2)" ::: "memory");
    __builtin_amdgcn_s_barrier();
    __builtin_amdgcn_sched_barrier(0);

    for (int t = 0; t < NT; ++t) {
        int tb = t + 1; if (tb >= NT) tb = 0;
        int ta = t + 2; if (ta >= NT) ta -= NT;
        stageB(tb, (t + 1) & 1);
        stageA(ta, (t + 2) % 3);

        const u16* Ab = lds + (t % 3) * 8192;
        const u16* Bb = lds + 24576 + (t & 1) * 16384;
#pragma unroll
        for (int ks = 0; ks < 2; ++ks) {
            bf16x8 a[4], b[4];
#pragma unroll
            for (int i = 0; i < 4; ++i) {
                const int ar = wr * 64 + i * 16 + lo;
                a[i] = *(const bf16x8*)&Ab[ar * 64 + (((ks * 4 + hi) ^ (ar & 7)) << 3)];
                const int br = wc * 64 + i * 16 + lo;
                b[i] = *(const bf16x8*)&Bb[br * 64 + (((ks * 4 + hi) ^ (br & 7)) << 3)];
            }
            __builtin_amdgcn_s_setprio(1);
#pragma unroll
            for (int i = 0; i < 4; ++i)
#pragma unroll
                for (int j = 0; j < 4; ++j)
                    acc[i][j] = __builtin_amdgcn_mfma_f32_16x16x32_bf16(
                                    a[i], b[j], acc[i][j], 0, 0, 0);
            __builtin_amdgcn_s_setprio(0);
        }
        __builtin_amdgcn_sched_barrier(0);
        asm volatile("s_waitcnt vmcnt(2)" ::: "memory");
        __builtin_amdgcn_s_barrier();
        __builtin_amdgcn_sched_barrier(0);
    }

    const int crow0 = m0 + wr * 64 + hi * 4;
    const int ccol0 = n0 + wc * 64 + lo;
#pragma unroll
    for (int j = 0; j < 4; ++j) {
        const int col = ccol0 + j * 16;
        float bj;
        float sc = 1.0f;
        if (MODE == 2) {
            bj = (col < 1024) ? bias[col]
               : (col < 2048) ? bias2[col - 1024] : bias3[col - 2048];
            if (col < 1024) sc = QSCALE;
        } else {
            bj = bias[col];
        }
#pragma unroll
        for (int i = 0; i < 4; ++i)
#pragma unroll
            for (int r = 0; r < 4; ++r) {
                float v = acc[i][j][r] + bj;
                if (MODE == 1) v = fmaxf(v, 0.f);
                if (MODE == 2) v *= sc;
                store_out(&C[(size_t)(crow0 + i * 16 + r) * N + col], v);
            }
    }
}

// ---------------------------------------------------------------------------
// Flash attention, swapped QK^T on 32x32x16 MFMA. Single-buffer, V hash
// swizzle. NEW: MFMA C-init = -mrun; single-read p arrays; no VGPR cap.
// ---------------------------------------------------------------------------
__global__ void attn_mfma_kernel(
    const u16* __restrict__ QKV, u16* __restrict__ O)
{
    __shared__ u16 Klds[64 * 64];   // [kv][dk], chunk ^ (row&7)
    __shared__ u16 Vlds[64 * 64];   // [dk][kv], chunk ^ hash(row)

    const int tid  = threadIdx.x;
    const int wave = tid >> 6;
    const int lane = tid & 63;
    const int l31  = lane & 31;
    const int hi5  = lane >> 5;
    const int b    = blockIdx.x >> 4;
    const int h    = blockIdx.x & 15;
    const int q0   = blockIdx.y * 128 + wave * 32;
    const size_t rowb = (size_t)b * SEQ * QKV_LD + (size_t)h * DKH;
    const u16* Qg = QKV + rowb;
    const u16* Kg = QKV + rowb + 1024;
    const u16* Vg = QKV + rowb + 2048;

    // Q as B-operand: col(q) = l31, k = 16f + 8*hi5 + e
    bf16x8 qf[4];
#pragma unroll
    for (int f = 0; f < 4; ++f)
        qf[f] = *(const bf16x8*)&Qg[(size_t)(q0 + l31) * QKV_LD + 16 * f + 8 * hi5];

    f32x16 oacc[2];
#pragma unroll
    for (int g = 0; g < 2; ++g)
#pragma unroll
        for (int r = 0; r < 16; ++r) oacc[g][r] = 0.f;
    float mrun = 0.f, lrun = 0.f;   // m_init = 0 (safe: |scores| << 100 exp2-units)

    const int krow = wave * 8 + (lane >> 3);
    const int kchk = ((lane & 7) ^ (lane >> 3)) << 3;
    u16* kdst = Klds + wave * 512;

    const int vdk0 = (tid & 15) * 4;
    const int vkv  = (tid >> 4) * 4;
    const int vchk = vkv >> 3;
    const int vsub = vkv & 7;

    const int ha = (l31 ^ (l31 >> 3)) & 7;
    const int hb = ha ^ 4;

    for (int kv0 = 0; kv0 < SEQ; kv0 += 64) {
        __syncthreads();
        gload16(Kg + (size_t)(kv0 + krow) * QKV_LD + kchk,      kdst);
        gload16(Kg + (size_t)(kv0 + krow + 32) * QKV_LD + kchk, kdst + 32 * 64);
        alignas(8) u16 e[4][4];
#pragma unroll
        for (int i = 0; i < 4; ++i)
            *(uint2*)e[i] = *(const uint2*)&Vg[(size_t)(kv0 + vkv + i) * QKV_LD + vdk0];
#pragma unroll
        for (int j = 0; j < 4; ++j) {
            alignas(8) u16 w4[4] = { e[0][j], e[1][j], e[2][j], e[3][j] };
            const int row = vdk0 + j;
            const int hsh = (row ^ (row >> 3)) & 7;
            *(uint2*)&Vlds[row * 64 + ((vchk ^ hsh) << 3) + vsub] = *(const uint2*)w4;
        }
        __syncthreads();

        // S^T - m = K·Q + C(-mrun): bias folded into the MFMA accumulator init
        f32x16 s0, s1;
        const float nm = -mrun;
#pragma unroll
        for (int r = 0; r < 16; ++r) { s0[r] = nm; s1[r] = nm; }
        __builtin_amdgcn_s_setprio(1);
#pragma unroll
        for (int f = 0; f < 4; ++f) {
            const int rc = ((2 * f + hi5) ^ (l31 & 7)) << 3;
            const bf16x8 ka = *(const bf16x8*)&Klds[l31 * 64 + rc];
            const bf16x8 kb = *(const bf16x8*)&Klds[(32 + l31) * 64 + rc];
            s0 = __builtin_amdgcn_mfma_f32_32x32x16_bf16(ka, qf[f], s0, 0, 0, 0);
            s1 = __builtin_amdgcn_mfma_f32_32x32x16_bf16(kb, qf[f], s1, 0, 0, 0);
        }
        __builtin_amdgcn_s_setprio(0);

        // single read of the accumulators into plain VGPR arrays
        float p0[16], p1[16];
#pragma unroll
        for (int r = 0; r < 16; ++r) { p0[r] = s0[r]; p1[r] = s1[r]; }

        // tree max over p (p = s - m_old)
        float mx[16];
#pragma unroll
        for (int r = 0; r < 16; ++r) mx[r] = fmaxf(p0[r], p1[r]);
#pragma unroll
        for (int off = 8; off >= 1; off >>= 1)
#pragma unroll
            for (int r = 0; r < off; ++r) mx[r] = fmaxf(mx[r], mx[r + off]);
        float tm = fmaxf(mx[0], __shfl_xor(mx[0], 32, 64));
        if (__any(tm > 8.0f)) {                 // defer-max (T13, THR=8)
            const float corr = exp2f(-tm);      // m_new = m_old + tm
            lrun *= corr;
#pragma unroll
            for (int g = 0; g < 2; ++g)
#pragma unroll
                for (int r = 0; r < 16; ++r) oacc[g][r] *= corr;
#pragma unroll
            for (int r = 0; r < 16; ++r) { p0[r] -= tm; p1[r] -= tm; }
            mrun += tm;
        }
        float sm[16];
#pragma unroll
        for (int r = 0; r < 16; ++r) {
            p0[r] = exp2f(p0[r]);
            p1[r] = exp2f(p1[r]);
            sm[r] = p0[r] + p1[r];
        }
#pragma unroll
        for (int off = 8; off >= 1; off >>= 1)
#pragma unroll
            for (int r = 0; r < off; ++r) sm[r] += sm[r + off];
        lrun += sm[0];

        // P B-frags via cvt_pk + permlane32_swap
        auto mkfrag = [&](float a0, float a1, float a2, float a3,
                          float a4, float a5, float a6, float a7) -> bf16x8 {
            uint32_t A, B, C, D;
            asm("v_cvt_pk_bf16_f32 %0, %1, %2" : "=v"(A) : "v"(a0), "v"(a1));
            asm("v_cvt_pk_bf16_f32 %0, %1, %2" : "=v"(C) : "v"(a2), "v"(a3));
            asm("v_cvt_pk_bf16_f32 %0, %1, %2" : "=v"(B) : "v"(a4), "v"(a5));
            asm("v_cvt_pk_bf16_f32 %0, %1, %2" : "=v"(D) : "v"(a6), "v"(a7));
            asm volatile("v_permlane32_swap_b32 %0, %1" : "+v"(A), "+v"(B));
            asm volatile("v_permlane32_swap_b32 %0, %1" : "+v"(C), "+v"(D));
            union { uint32_t w[4]; bf16x8 v; } u;
            u.w[0] = A; u.w[1] = C; u.w[2] = B; u.w[3] = D;
            return u.v;
        };
        bf16x8 pb0 = mkfrag(p0[0], p0[1], p0[2],  p0[3],  p0[4],  p0[5],  p0[6],  p0[7]);
        bf16x8 pb1 = mkfrag(p0[8], p0[9], p0[10], p0[11], p0[12], p0[13], p0[14], p0[15]);
        bf16x8 pb2 = mkfrag(p1[0], p1[1], p1[2],  p1[3],  p1[4],  p1[5],  p1[6],  p1[7]);
        bf16x8 pb3 = mkfrag(p1[8], p1[9], p1[10], p1[11], p1[12], p1[13], p1[14], p1[15]);

        // O^T += V^T · P
        __builtin_amdgcn_s_setprio(1);
#pragma unroll
        for (int f = 0; f < 4; ++f) {
            const bf16x8 pf = (f == 0) ? pb0 : (f == 1) ? pb1 : (f == 2) ? pb2 : pb3;
            const int ca = ((2 * f + hi5) ^ ha) << 3;
            const int cb = ((2 * f + hi5) ^ hb) << 3;
            const bf16x8 va = *(const bf16x8*)&Vlds[l31 * 64 + ca];
            const bf16x8 vb = *(const bf16x8*)&Vlds[(32 + l31) * 64 + cb];
            oacc[0] = __builtin_amdgcn_mfma_f32_32x32x16_bf16(va, pf, oacc[0], 0, 0, 0);
            oacc[1] = __builtin_amdgcn_mfma_f32_32x32x16_bf16(vb, pf, oacc[1], 0, 0, 0);
        }
        __builtin_amdgcn_s_setprio(0);
    }

    lrun += __shfl_xor(lrun, 32, 64);
    const float inv = 1.0f / lrun;
    u16* Orow = O + (size_t)b * SEQ * D_MODEL + (size_t)(q0 + l31) * D_MODEL + h * DKH;
#pragma unroll
    for (int g = 0; g < 2; ++g)
#pragma unroll
        for (int rp = 0; rp < 8; ++rp) {
            const int r = rp * 2;
            const float v0 = oacc[g][r] * inv;
            const float v1 = oacc[g][r + 1] * inv;
            uint32_t pk;
            asm("v_cvt_pk_bf16_f32 %0, %1, %2" : "=v"(pk) : "v"(v0), "v"(v1));
            const int d = 32 * g + (r & 3) + 8 * (r >> 2) + 4 * hi5;
            *(uint32_t*)&Orow[d] = pk;
        }
}

// ---------------------------------------------------------------------------
// Batched 1024x1024 transpose: z selects (Wq,Wk,Wv,Wo) -> bf16 [N][K]
// ---------------------------------------------------------------------------
__global__ __launch_bounds__(256) void transpose_w4_kernel(
    const float* __restrict__ W0, const float* __restrict__ W1,
    const float* __restrict__ W2, const float* __restrict__ W3,
    u16* __restrict__ D0, u16* __restrict__ D1,
    u16* __restrict__ D2, u16* __restrict__ D3)
{
    const int z = blockIdx.z;
    const float* W = (z == 0) ? W0 : (z == 1) ? W1 : (z == 2) ? W2 : W3;
    u16*       Wt = (z == 0) ? D0 : (z == 1) ? D1 : (z == 2) ? D2 : D3;

    __shared__ float t[32][33];
    const int n0 = blockIdx.x << 5;
    const int k0 = blockIdx.y << 5;
    const int tx = threadIdx.x & 31;
    const int ty = threadIdx.x >> 5;
#pragma unroll
    for (int i = 0; i < 4; ++i)
        t[ty + i * 8][tx] = W[(size_t)(k0 + ty + i * 8) * D_MODEL + n0 + tx];
    __syncthreads();
#pragma unroll
    for (int i = 0; i < 4; ++i)
        Wt[(size_t)(n0 + ty + i * 8) * D_MODEL + k0 + tx] = f2bf(t[tx][ty + i * 8]);
}

// W[K][N] f32 -> Wt[N][K] bf16 (generic tiled 32x32 transpose)
__global__ __launch_bounds__(256) void transpose_w_kernel(
    const float* __restrict__ W, u16* __restrict__ Wt, int K, int N)
{
    __shared__ float t[32][33];
    const int n0 = blockIdx.x << 5;
    const int k0 = blockIdx.y << 5;
    const int tx = threadIdx.x & 31;
    const int ty = threadIdx.x >> 5;
#pragma unroll
    for (int i = 0; i < 4; ++i)
        t[ty + i * 8][tx] = W[(size_t)(k0 + ty + i * 8) * N + n0 + tx];
    __syncthreads();
#pragma unroll
    for (int i = 0; i < 4; ++i)
        Wt[(size_t)(n0 + ty + i * 8) * K + k0 + tx] = f2bf(t[tx][ty + i * 8]);
}

// f32 -> bf16 bulk convert, 8 elems/thread
__global__ __launch_bounds__(256) void cvt_kernel(
    const float* __restrict__ src, u16* __restrict__ dst)
{
    const size_t i = ((size_t)blockIdx.x * 256 + threadIdx.x) * 8;
    const float4 a = *(const float4*)&src[i];
    const float4 b = *(const float4*)&src[i + 4];
    alignas(16) u16 e[8] = { f2bf(a.x), f2bf(a.y), f2bf(a.z), f2bf(a.w),
                             f2bf(b.x), f2bf(b.y), f2bf(b.z), f2bf(b.w) };
    *(int4*)&dst[i] = *(const int4*)e;
}

// ---------------------------------------------------------------------------
// out = LayerNorm(X + Y)*gamma + beta; mixed dtypes. One block per row.
// ---------------------------------------------------------------------------
__device__ __forceinline__ float4 ld4(const float* p) { return *(const float4*)p; }
__device__ __forceinline__ float4 ld4(const u16* p) {
    alignas(8) u16 e[4];
    *(uint2*)e = *(const uint2*)p;
    return make_float4(bf2f(e[0]), bf2f(e[1]), bf2f(e[2]), bf2f(e[3]));
}
__device__ __forceinline__ void st4(float* p, float4 v) { *(float4*)p = v; }
__device__ __forceinline__ void st4(u16* p, float4 v) {
    alignas(8) u16 e[4] = { f2bf(v.x), f2bf(v.y), f2bf(v.z), f2bf(v.w) };
    *(uint2*)p = *(const uint2*)e;
}

template <typename XT, typename YT, typename OT>
__global__ __launch_bounds__(256) void add_ln_kernel(
    const XT* __restrict__ X, const YT* __restrict__ Y,
    const float* __restrict__ gamma, const float* __restrict__ beta,
    OT* __restrict__ Out)
{
    const int row = blockIdx.x;
    const int i0  = threadIdx.x << 2;
    const float4 xv = ld4(X + (size_t)row * D_MODEL + i0);
    const float4 yv = ld4(Y + (size_t)row * D_MODEL + i0);
    const float4 v  = make_float4(xv.x + yv.x, xv.y + yv.y, xv.z + yv.z, xv.w + yv.w);

    float s1 = v.x + v.y + v.z + v.w;
    float s2 = v.x * v.x + v.y * v.y + v.z * v.z + v.w * v.w;
#pragma unroll
    for (int off = 32; off > 0; off >>= 1) {
        s1 += __shfl_xor(s1, off, 64);
        s2 += __shfl_xor(s2, off, 64);
    }
    __shared__ float red[8];
    const int wid = threadIdx.x >> 6;
    if ((threadIdx.x & 63) == 0) { red[wid] = s1; red[wid + 4] = s2; }
    __syncthreads();
    s1 = red[0] + red[1] + red[2] + red[3];
    s2 = red[4] + red[5] + red[6] + red[7];

    const float mu   = s1 * (1.0f / D_MODEL);
    const float var  = s2 * (1.0f / D_MODEL) - mu * mu;
    const float rstd = rsqrtf(var + LN_EPS);

    const float4 g  = *(const float4*)(gamma + i0);
    const float4 bb = *(const float4*)(beta + i0);
    float4 ov;
    ov.x = (v.x - mu) * rstd * g.x + bb.x;
    ov.y = (v.y - mu) * rstd * g.y + bb.y;
    ov.z = (v.z - mu) * rstd * g.z + bb.z;
    ov.w = (v.w - mu) * rstd * g.w + bb.w;
    st4(Out + (size_t)row * D_MODEL + i0, ov);
}

// ---------------------------------------------------------------------------
extern "C" void kernel_launch(void* const* d_in, const int* in_sizes, int n_in,
                              void* d_out, int out_size, void* d_ws, size_t ws_size,
                              hipStream_t stream)
{
    const float* x     = (const float*)d_in[0];
    const float* Wq    = (const float*)d_in[1];
    const float* bq    = (const float*)d_in[2];
    const float* Wk    = (const float*)d_in[3];
    const float* bk    = (const float*)d_in[4];
    const float* Wv    = (const float*)d_in[5];
    const float* bv    = (const float*)d_in[6];
    const float* Wo    = (const float*)d_in[7];
    const float* bo    = (const float*)d_in[8];
    const float* W1    = (const float*)d_in[9];
    const float* b1    = (const float*)d_in[10];
    const float* W2    = (const float*)d_in[11];
    const float* b2    = (const float*)d_in[12];
    const float* g1    = (const float*)d_in[13];
    const float* beta1 = (const float*)d_in[14];
    const float* g2    = (const float*)d_in[15];
    const float* beta2 = (const float*)d_in[16];
    float* out = (float*)d_out;

    const size_t TOKD = (size_t)NTOK * D_MODEL;
    u16* xb    = (u16*)d_ws;
    u16* wqkvT = xb + TOKD;                              // [3072][1024]
    u16* woT   = wqkvT + (size_t)3 * D_MODEL * D_MODEL;
    u16* w1T   = woT + (size_t)D_MODEL * D_MODEL;        // [4096][1024]
    u16* w2T   = w1T + (size_t)D_MODEL * D_FF;           // [1024][4096]
    u16* qkv   = w2T + (size_t)D_FF * D_MODEL;           // [NTOK][3072]
    u16* ctx   = qkv + (size_t)NTOK * QKV_LD;
    u16* y1    = ctx + TOKD;
    u16* x2    = y1;                                     // LN1 in place
    u16* h1    = qkv;                                    // spans qkv+ctx

    const dim3 blk(256);
    const dim3 blk5(512);

    cvt_kernel<<<dim3(TOKD / 2048), blk, 0, stream>>>(x, xb);
    transpose_w4_kernel<<<dim3(32, 32, 4), blk, 0, stream>>>(
        Wq, Wk, Wv, Wo,
        wqkvT, wqkvT + (size_t)D_MODEL * D_MODEL,
        wqkvT + (size_t)2 * D_MODEL * D_MODEL, woT);
    transpose_w_kernel<<<dim3(D_FF / 32,    D_MODEL / 32), blk, 0, stream>>>(W1, w1T, D_MODEL, D_FF);
    transpose_w_kernel<<<dim3(D_MODEL / 32, D_FF / 32),    blk, 0, stream>>>(W2, w2T, D_FF, D_MODEL);

    // fused QKV projection (Q pre-scaled for exp2 softmax)
    gemm_pipe_kernel<2, u16><<<dim3(QKV_LD / 256, NTOK / 128), blk5, 0, stream>>>(
        xb, wqkvT, bq, bk, bv, qkv, NTOK, QKV_LD, D_MODEL);

    attn_mfma_kernel<<<dim3(BATCH * N_HEADS, SEQ / 128), blk, 0, stream>>>(qkv, ctx);

    gemm_pipe_kernel<0, u16><<<dim3(D_MODEL / 256, NTOK / 128), blk5, 0, stream>>>(
        ctx, woT, bo, bo, bo, y1, NTOK, D_MODEL, D_MODEL);

    add_ln_kernel<float, u16, u16><<<dim3(NTOK), blk, 0, stream>>>(x, y1, g1, beta1, x2);

    gemm_pipe_kernel<1, u16><<<dim3(D_FF / 256, NTOK / 128), blk5, 0, stream>>>(
        x2, w1T, b1, b1, b1, h1, NTOK, D_FF, D_MODEL);
    gemm_pipe_kernel<0, float><<<dim3(D_MODEL / 256, NTOK / 128), blk5, 0, stream>>>(
        h1, w2T, b2, b2, b2, out, NTOK, D_MODEL, D_FF);

    add_ln_kernel<u16, float, float><<<dim3(NTOK), blk, 0, stream>>>(x2, out, g2, beta2, out);

    (void)in_sizes; (void)n_in; (void)out_size; (void)ws_size;
}